// Round 14
// baseline (1372.598 us; speedup 1.0000x reference)
//
#include <hip/hip_runtime.h>
#include <hip/hip_bf16.h>
#include <math.h>

#define NN 50000
#define EE 200000
#define ET 250000   // EE + NN self loops
#define GG 64
#define LL 6

using short8 = __attribute__((ext_vector_type(8))) short;
using f32x4  = __attribute__((ext_vector_type(4))) float;
typedef unsigned short ushortT;

__device__ __forceinline__ float elu1(float x) { return x > 0.f ? x : expm1f(x); }
__device__ __forceinline__ float gelu_exact(float x) {
    return 0.5f * x * (1.f + erff(x * 0.70710678118654752440f));
}
__device__ __forceinline__ short f2bf(float f) {
    __hip_bfloat16 h = __float2bfloat16(f);
    return *reinterpret_cast<short*>(&h);
}
__device__ __forceinline__ float bf2f(ushortT u) {
    return __uint_as_float(((unsigned)u) << 16);
}
__device__ __forceinline__ void accum8(float* acc, float a, uint4 d) {
    acc[0] += a * bf2f((ushortT)(d.x & 0xffff));
    acc[1] += a * bf2f((ushortT)(d.x >> 16));
    acc[2] += a * bf2f((ushortT)(d.y & 0xffff));
    acc[3] += a * bf2f((ushortT)(d.y >> 16));
    acc[4] += a * bf2f((ushortT)(d.z & 0xffff));
    acc[5] += a * bf2f((ushortT)(d.z >> 16));
    acc[6] += a * bf2f((ushortT)(d.w & 0xffff));
    acc[7] += a * bf2f((ushortT)(d.w >> 16));
}

// ---------------- CSR build ----------------
__global__ void count_deg_kernel(const int* __restrict__ ei, int* __restrict__ deg) {
    int e = blockIdx.x * 256 + threadIdx.x;
    if (e >= ET) return;
    int dst = (e < EE) ? ei[EE + e] : (e - EE);
    atomicAdd(&deg[dst], 1);
}

__global__ void scan_kernel(const int* __restrict__ deg, int* __restrict__ row_ptr, int n) {
    __shared__ int s[1024];
    int tid = threadIdx.x;
    const int per = (n + 1023) / 1024;
    int lo = tid * per, hi = min(lo + per, n);
    int sum = 0;
    for (int i = lo; i < hi; i++) sum += deg[i];
    s[tid] = sum;
    __syncthreads();
    for (int off = 1; off < 1024; off <<= 1) {
        int t = (tid >= off) ? s[tid - off] : 0;
        __syncthreads();
        s[tid] += t;
        __syncthreads();
    }
    int run = s[tid] - sum;
    for (int i = lo; i < hi; i++) { row_ptr[i] = run; run += deg[i]; }
    if (tid == 1023) row_ptr[n] = s[1023];
}

__global__ void fill_csr_kernel(const int* __restrict__ ei, const int* __restrict__ row_ptr,
                                int* __restrict__ cursor, int* __restrict__ edge_src) {
    int e = blockIdx.x * 256 + threadIdx.x;
    if (e >= ET) return;
    int src, dst;
    if (e < EE) { src = ei[e]; dst = ei[EE + e]; }
    else        { src = e - EE; dst = e - EE; }
    int pos = atomicAdd(&cursor[dst], 1);
    edge_src[row_ptr[dst] + pos] = src;
}

__global__ void dinv_kernel(const int* __restrict__ row_ptr, float* __restrict__ dinv) {
    int n = blockIdx.x * 256 + threadIdx.x;
    if (n >= NN) return;
    int d = row_ptr[n + 1] - row_ptr[n];
    dinv[n] = (d > 0) ? rsqrtf((float)d) : 0.f;
}

// ---- BLOCK-LOCAL degree sort (64-node windows) ----------------------------
// R8 WIN: agg 134->124us, FETCH 155MB (R4-level locality + deg-uniform waves).
__global__ __launch_bounds__(256) void local_sort_kernel(
    const int* __restrict__ row_ptr, int* __restrict__ perm, int n_nodes) {
    int g = blockIdx.x * 4 + (threadIdx.x >> 6);
    int l = threadIdx.x & 63;
    int node = g * 64 + l;
    if (g * 64 >= n_nodes) return;
    int d = (node < n_nodes) ? (row_ptr[node + 1] - row_ptr[node]) : 0x7fffffff;
    int rank = 0;
#pragma unroll 16
    for (int j = 0; j < 64; j++) {
        int dj = __shfl(d, j);
        rank += (dj < d) || (dj == d && j < l);
    }
    if (node < n_nodes) perm[g * 64 + rank] = node;
}

// ---- fold wv into wo: Wvo = wv@wo, bvo = bv@wo + bo (fp32, exact) ----
__global__ void wvwo_kernel(const float* __restrict__ wv, const float* __restrict__ wo,
                            const float* __restrict__ bv, const float* __restrict__ bo,
                            float* __restrict__ Wvo, float* __restrict__ bvo) {
    int l = blockIdx.y;
    const float* Wv = wv + l * 16384;
    const float* Wo = wo + l * 16384;
    int tid = blockIdx.x * 256 + threadIdx.x;
    if (tid < 16384) {
        int r = tid >> 7, c = tid & 127;
        float s = 0.f;
        for (int k = 0; k < 128; k++) s += Wv[r * 128 + k] * Wo[k * 128 + c];
        Wvo[l * 16384 + tid] = s;
    }
    if (blockIdx.x == 0 && threadIdx.x < 128) {
        int c = threadIdx.x;
        float s = bo[l * 128 + c];
        for (int k = 0; k < 128; k++) s += bv[l * 128 + k] * Wo[k * 128 + c];
        bvo[l * 128 + c] = s;
    }
}

// ---- weight prep: fp32 [K,N] (ldb) -> bf16 MFMA B-fragment order ----
__global__ void bprep_kernel(const float* __restrict__ B, short* __restrict__ Bp,
                             int K, int N, int ldb, long srcStride) {
    int layer = blockIdx.y;
    const float* Bsrc = B + srcStride * layer;
    short* Bd = Bp + (size_t)K * N * layer;
    int total = (K >> 5) * (N >> 4) * 64;
    int tid = blockIdx.x * 256 + threadIdx.x;
    if (tid >= total) return;
    int l = tid & 63;
    int rest = tid >> 6;
    int kbc = K >> 5;
    int kb = rest % kbc;
    int c16 = rest / kbc;
    int n = c16 * 16 + (l & 15);
    int kbase = kb * 32 + (l >> 4) * 8;
    short v[8];
#pragma unroll
    for (int j = 0; j < 8; j++) v[j] = f2bf(Bsrc[(size_t)(kbase + j) * ldb + n]);
    *(uint4*)(Bd + (size_t)tid * 8) = *(uint4*)v;
}

__global__ void cast_bf16_kernel(const float* __restrict__ in, short* __restrict__ out, int n4) {
    int i = blockIdx.x * 256 + threadIdx.x;
    if (i >= n4) return;
    float4 v = *(const float4*)(in + (size_t)i * 4);
    short s[4] = { f2bf(v.x), f2bf(v.y), f2bf(v.z), f2bf(v.w) };
    *(uint2*)(out + (size_t)i * 4) = *(uint2*)s;
}

// ---------------- MFMA GEMM, LDS B-staging, XCD-aware column-fast split -----
// TMAJ: store bf16 C tile-major [col/32][row][32]. ATILE32: A tile-major.
// EPI: 0 plain, 2 asad + store
template <int EPI, bool BIAS, bool OUTBF16, int NSPLIT, int KBC,
          bool TMAJ = false, bool ATILE32 = false>
__global__ __launch_bounds__(256) void gemm_bf16_kernel(
    const short* __restrict__ A, const short* __restrict__ Bp,
    const float* __restrict__ bias, void* __restrict__ Cv,
    const float* __restrict__ a_s, const float* __restrict__ a_d,
    float* __restrict__ as_out, float* __restrict__ ad_out, int asH,
    int M, int K, int Nc) {
    __shared__ short Bs[(KBC > 0) ? KBC * 4096 : 8192];
    int t = threadIdx.x;
    int w = t >> 6, l = t & 63;
    int ln = l & 15, lq = l >> 4;
    int MBceil = (M + 63) >> 6;
    int bx = blockIdx.x;
    int xcd = bx & 7, idx = bx >> 3;
    int t2 = idx % NSPLIT;
    int mb = (idx / NSPLIT) * 8 + xcd;
    if (mb >= MBceil) return;
    int bm = mb * 64 + w * 16;
    int arow = bm + ln;
    bool aok = arow < M;
    int rowb = bm + lq * 4;
    const short* Ap = A + (size_t)arow * K + lq * 8;

    auto aload = [&](int kb) -> short8 {
        if (!aok) return (short8){0, 0, 0, 0, 0, 0, 0, 0};
        const short* p;
        if constexpr (ATILE32)
            p = A + ((size_t)kb * M + arow) * 32 + lq * 8;
        else
            p = Ap + kb * 32;
        return *(const short8*)p;
    };

    f32x4 acc[8];
#pragma unroll
    for (int j = 0; j < 8; j++) acc[j] = (f32x4){0.f, 0.f, 0.f, 0.f};

    if constexpr (KBC > 0) {
        {
            const uint4* src = (const uint4*)(Bp + (size_t)t2 * KBC * 4096);
            uint4* dst = (uint4*)Bs;
#pragma unroll
            for (int i = 0; i < KBC * 2; i++)
                dst[i * 256 + t] = src[i * 256 + t];
        }
        short8 af[KBC];
#pragma unroll
        for (int kb = 0; kb < KBC; kb++)
            af[kb] = aload(kb);
        __syncthreads();
#pragma unroll
        for (int kb = 0; kb < KBC; kb++)
#pragma unroll
            for (int ct = 0; ct < 8; ct++) {
                short8 bfr = *(const short8*)(Bs + ((ct * KBC + kb) * 64 + l) * 8);
                acc[ct] = __builtin_amdgcn_mfma_f32_16x16x32_bf16(af[kb], bfr, acc[ct], 0, 0, 0);
            }
    } else {
        int kbc = K >> 5;
        int sct = t >> 5, spart = t & 31;
        auto stage = [&](int buf, int kb) {
            const uint4* src = (const uint4*)(Bp + ((size_t)(t2 * 8 + sct) * kbc + kb) * 512);
            uint4* dst = (uint4*)(Bs + buf * 4096 + sct * 512);
            dst[spart * 2]     = src[spart * 2];
            dst[spart * 2 + 1] = src[spart * 2 + 1];
        };
        stage(0, 0);
        __syncthreads();
        for (int kb = 0; kb < kbc; kb++) {
            if (kb + 1 < kbc) stage((kb + 1) & 1, kb + 1);
            short8 af = aload(kb);
            const short* bsb = Bs + (kb & 1) * 4096;
#pragma unroll
            for (int ct = 0; ct < 8; ct++) {
                short8 bfr = *(const short8*)(bsb + (ct * 64 + l) * 8);
                acc[ct] = __builtin_amdgcn_mfma_f32_16x16x32_bf16(af, bfr, acc[ct], 0, 0, 0);
            }
            __syncthreads();
        }
    }

    if (EPI == 2) {
        const float* asv = a_s + t2 * 128;
        const float* adv = a_d + t2 * 128;
#pragma unroll
        for (int reg = 0; reg < 4; reg++) {
            float vs = 0.f, vd = 0.f;
#pragma unroll
            for (int ct = 0; ct < 8; ct++) {
                int colL = ct * 16 + ln;
                float av = acc[ct][reg];
                vs += av * asv[colL];
                vd += av * adv[colL];
            }
            vs += __shfl_xor(vs, 1); vs += __shfl_xor(vs, 2);
            vs += __shfl_xor(vs, 4); vs += __shfl_xor(vs, 8);
            vd += __shfl_xor(vd, 1); vd += __shfl_xor(vd, 2);
            vd += __shfl_xor(vd, 4); vd += __shfl_xor(vd, 8);
            int row = rowb + reg;
            if (ln == 0 && row < M) {
                as_out[(size_t)row * asH + t2] = vs;
                ad_out[(size_t)row * asH + t2] = vd;
            }
        }
    }
#pragma unroll
    for (int ct = 0; ct < 8; ct++) {
        int col = t2 * 128 + ct * 16 + ln;
        float bv_ = BIAS ? bias[col] : 0.f;
#pragma unroll
        for (int reg = 0; reg < 4; reg++) {
            int row = rowb + reg;
            if (row < M) {
                float v = acc[ct][reg] + bv_;
                if (OUTBF16) {
                    size_t addr;
                    if constexpr (TMAJ)
                        addr = ((size_t)(col >> 5) * M + row) * 32 + (col & 31);
                    else
                        addr = (size_t)row * Nc + col;
                    ((__hip_bfloat16*)Cv)[addr] = __float2bfloat16(v);
                } else {
                    ((float*)Cv)[(size_t)row * Nc + col] = v;
                }
            }
        }
    }
}

// ---- fully fused 6-layer transformer, BARRIER-FREE ------------------------
// R10-R13 lesson chain: fused kernel is stall-bound on its ~108-216 block
// barriers, and co-residency is GRID-CAPPED at 784 blocks (~3 blocks/CU =
// 12 waves/CU) -- no LDS/VGPR tuning can add a 4th block (R13: occ 18.6%
// despite 4-blk/CU capacity). Fix: remove ALL barriers. The only reason for
// __syncthreads was the shared Bs weight stage; instead read each MFMA's
// B-fragment DIRECTLY from global -- prepped weights are 1.7MB total,
// L2-resident on every XCD; per-MFMA the wave reads a coalesced 1KB
// fragment (16B/lane, same fragment indexing as the staged path). L2 math:
// 288KB/layer/wave x 6 x 3136 waves = 5.4GB / 34.5TB/s = ~157us, overlapped
// with ~95us of MFMA. Ts bounce is wave-private (wave-synchronous LDS, no
// barrier). LDS = 17408B.
#define TS 136
__global__ __launch_bounds__(256) void transformer_fused_kernel(
    const short* __restrict__ Qb, const short* __restrict__ Wvop,
    const float* __restrict__ bvo, const short* __restrict__ wf1p,
    const short* __restrict__ wf2p, const float* __restrict__ bf1,
    const float* __restrict__ bf2, const float* __restrict__ ln1g,
    const float* __restrict__ ln1b, const float* __restrict__ ln2g,
    const float* __restrict__ ln2b, float* __restrict__ fQ, int M) {
    __shared__ short Ts[4][16 * TS];     // per-wave bounce only (no Bs!)
    int t = threadIdx.x;
    int w = t >> 6, l = t & 63;
    int ln = l & 15, lq = l >> 4;
    int MBceil = (M + 63) >> 6;
    int bx = blockIdx.x;
    int xcd = bx & 7, mb = (bx >> 3) * 8 + xcd;
    if (mb >= MBceil) return;
    int bm = mb * 64 + w * 16;
    int rowb = bm + lq * 4;
    short* Tw = &Ts[w][0];

    // load state as C-fragments (col=ct*16+ln, row=rowb+reg)
    ushortT hc[8][4];
#pragma unroll
    for (int ct = 0; ct < 8; ct++) {
        int col = ct * 16 + ln;
#pragma unroll
        for (int reg = 0; reg < 4; reg++) {
            int row = rowb + reg;
            hc[ct][reg] = (row < M) ? ((const ushortT*)Qb)[(size_t)row * 128 + col] : 0;
        }
    }

    // bounce hc (C-frag) -> A-frags via wave-private LDS tile
    auto bounceA = [&](short8* a) {
#pragma unroll
        for (int ct = 0; ct < 8; ct++)
#pragma unroll
            for (int reg = 0; reg < 4; reg++)
                Tw[(lq * 4 + reg) * TS + ct * 16 + ln] = (short)hc[ct][reg];
#pragma unroll
        for (int kb = 0; kb < 4; kb++)
            a[kb] = *(const short8*)(Tw + ln * TS + kb * 32 + lq * 8);
    };
    // B-fragment straight from global (L2-hit): frag = fragment id in the
    // bprep layout; coalesced 16B/lane.
    auto bload = [&](const short* wp, int frag) -> short8 {
        return *(const short8*)(wp + ((size_t)frag * 64 + l) * 8);
    };
    // residual + bias + LayerNorm over 128 cols; updates hc (bf16-rounded)
    auto lnEpi = [&](f32x4* acc, const float* bias, const float* g,
                     const float* b, bool writeF) {
        float v[8][4];
#pragma unroll
        for (int ct = 0; ct < 8; ct++) {
            float bv_ = bias[ct * 16 + ln];
#pragma unroll
            for (int reg = 0; reg < 4; reg++)
                v[ct][reg] = acc[ct][reg] + bv_ + bf2f(hc[ct][reg]);
        }
#pragma unroll
        for (int reg = 0; reg < 4; reg++) {
            float s = 0.f;
#pragma unroll
            for (int ct = 0; ct < 8; ct++) s += v[ct][reg];
            s += __shfl_xor(s, 1); s += __shfl_xor(s, 2);
            s += __shfl_xor(s, 4); s += __shfl_xor(s, 8);
            float mean = s * (1.f / 128.f);
            float s2 = 0.f;
#pragma unroll
            for (int ct = 0; ct < 8; ct++) { float d = v[ct][reg] - mean; s2 += d * d; }
            s2 += __shfl_xor(s2, 1); s2 += __shfl_xor(s2, 2);
            s2 += __shfl_xor(s2, 4); s2 += __shfl_xor(s2, 8);
            float rstd = rsqrtf(s2 * (1.f / 128.f) + 1e-5f);
            int row = rowb + reg;
#pragma unroll
            for (int ct = 0; ct < 8; ct++) {
                int col = ct * 16 + ln;
                float o = (v[ct][reg] - mean) * rstd * g[col] + b[col];
                hc[ct][reg] = (ushortT)f2bf(o);
                if (writeF && row < M) fQ[(size_t)row * 128 + col] = o;
            }
        }
    };

    for (int lay = 0; lay < LL; lay++) {
        // ---------- g1: acc1 = h @ Wvo ----------
        short8 a1[4];
        bounceA(a1);
        const short* wvl = Wvop + (size_t)lay * 16384;
        f32x4 acc1[8];
#pragma unroll
        for (int j = 0; j < 8; j++) acc1[j] = (f32x4){0.f, 0.f, 0.f, 0.f};
#pragma unroll
        for (int kb = 0; kb < 4; kb++)
#pragma unroll
            for (int ct = 0; ct < 8; ct++) {
                short8 bfr = bload(wvl, ct * 4 + kb);
                acc1[ct] = __builtin_amdgcn_mfma_f32_16x16x32_bf16(a1[kb], bfr, acc1[ct], 0, 0, 0);
            }
        lnEpi(acc1, bvo + lay * 128, ln1g + lay * 128, ln1b + lay * 128, false);

        // ---------- FF: acc2 = gelu(h@wf1+b1) @ wf2 ----------
        short8 af1[4];
        bounceA(af1);
        const short* w1l = wf1p + (size_t)lay * 65536;
        const short* w2l = wf2p + (size_t)lay * 65536;
        f32x4 acc2[8];
#pragma unroll
        for (int j = 0; j < 8; j++) acc2[j] = (f32x4){0.f, 0.f, 0.f, 0.f};
        for (int kc = 0; kc < 4; kc++) {
            f32x4 acct[8];
#pragma unroll
            for (int j = 0; j < 8; j++) acct[j] = (f32x4){0.f, 0.f, 0.f, 0.f};
#pragma unroll
            for (int kb = 0; kb < 4; kb++)
#pragma unroll
                for (int ct = 0; ct < 8; ct++) {
                    short8 bfr = bload(w1l, kc * 32 + ct * 4 + kb);
                    acct[ct] = __builtin_amdgcn_mfma_f32_16x16x32_bf16(af1[kb], bfr, acct[ct], 0, 0, 0);
                }
            // gelu + bias -> wave-private T (bf16) -> A2 frags
            const float* bfc = bf1 + lay * 512 + kc * 128;
#pragma unroll
            for (int ct = 0; ct < 8; ct++) {
                float bv = bfc[ct * 16 + ln];
#pragma unroll
                for (int reg = 0; reg < 4; reg++)
                    Tw[(lq * 4 + reg) * TS + ct * 16 + ln] = f2bf(gelu_exact(acct[ct][reg] + bv));
            }
            short8 a2[4];
#pragma unroll
            for (int kb2 = 0; kb2 < 4; kb2++)
                a2[kb2] = *(const short8*)(Tw + ln * TS + kb2 * 32 + lq * 8);
#pragma unroll
            for (int kb2 = 0; kb2 < 4; kb2++)
#pragma unroll
                for (int ct = 0; ct < 8; ct++) {
                    short8 bfr = bload(w2l, ct * 16 + kc * 4 + kb2);
                    acc2[ct] = __builtin_amdgcn_mfma_f32_16x16x32_bf16(a2[kb2], bfr, acc2[ct], 0, 0, 0);
                }
        }
        lnEpi(acc2, bf2 + lay * 128, ln2g + lay * 128, ln2b + lay * 128, lay == LL - 1);
    }
}

// ---- GAT softmax phase: exact 2-pass per (node, head), 1 wave/node --------
template <int H>
__global__ __launch_bounds__(256) void gat_alpha_kernel(
    const float* __restrict__ as_, const float* __restrict__ ad_,
    const int* __restrict__ row_ptr, const int* __restrict__ edge_src,
    float* __restrict__ exA, float* __restrict__ exS, int n_nodes) {
    const int GS = 64 / H;
    int node = blockIdx.x * 4 + (threadIdx.x >> 6);
    if (node >= n_nodes) return;
    int l = threadIdx.x & 63;
    int h = l / GS;
    int lig = l % GS;
    int start = row_ptr[node];
    int deg = row_ptr[node + 1] - start;
    float adn = ad_[(size_t)node * H + h];
    float m = -1e30f;
    for (int j = lig; j < deg; j += GS) {
        int s = edge_src[start + j];
        float e = as_[(size_t)s * H + h] + adn;
        e = e > 0.f ? e : 0.2f * e;
        m = fmaxf(m, e);
    }
#pragma unroll
    for (int mask = 1; mask < GS; mask <<= 1)
        m = fmaxf(m, __shfl_xor(m, mask));
    float S = 0.f;
    for (int j = lig; j < deg; j += GS) {
        int s = edge_src[start + j];
        float e = as_[(size_t)s * H + h] + adn;
        e = e > 0.f ? e : 0.2f * e;
        float ex = expf(e - m);
        exA[(size_t)h * ET + (start + j)] = ex;
        S += ex;
    }
#pragma unroll
    for (int mask = 1; mask < GS; mask <<= 1)
        S += __shfl_xor(S, mask);
    if (lig == 0) exS[(size_t)h * n_nodes + node] = S;
}

// ---- tiled GAT aggregation: 32-col tiles, XCD-pinned, local-deg-sorted ----
__global__ __launch_bounds__(256) void gat_agg_tiled_kernel(
    const ushortT* __restrict__ hT, const float* __restrict__ exA,
    const float* __restrict__ exS, const float* __restrict__ bias,
    const int* __restrict__ row_ptr, const int* __restrict__ edge_src,
    const int* __restrict__ perm,
    __hip_bfloat16* __restrict__ outT, int n_nodes, int NB) {
    int bx = blockIdx.x;
    int xcd = bx & 7, rest = bx >> 3;
    int tl = rest / NB, nb = rest - tl * NB;
    int tile = tl * 8 + xcd;
    int nl = threadIdx.x >> 2, q = threadIdx.x & 3;
    int idx = nb * 64 + nl;
    if (idx >= n_nodes) return;
    int node = perm[idx];
    int hb = tile >> 2;
    const ushortT* __restrict__ base = hT + (size_t)tile * n_nodes * 32 + q * 8;
    const float* __restrict__ exAh = exA + (size_t)hb * ET;
    int start = row_ptr[node];
    int deg = row_ptr[node + 1] - start;
    float acc[8];
#pragma unroll
    for (int c = 0; c < 8; c++) acc[c] = 0.f;
    for (int j = 0; j < deg; j++) {
        int s = edge_src[start + j];
        float a = exAh[start + j];
        uint4 d = *(const uint4*)(base + (size_t)s * 32);
        accum8(acc, a, d);
    }
    float inv = 1.f / (exS[(size_t)hb * n_nodes + node] + 1e-16f);
    const float* bp = bias + tile * 32 + q * 8;
    short o[8];
#pragma unroll
    for (int c = 0; c < 8; c++)
        o[c] = f2bf(elu1(acc[c] * inv + bp[c]));
    *(uint4*)(outT + ((size_t)tile * n_nodes + node) * 32 + q * 8) = *(uint4*)o;
}

// ---------------- GCN aggregation (bf16 in, row-major) -> bf16 Qb -----------
__global__ __launch_bounds__(256, 2) void gcn_agg_kernel(
    const ushortT* __restrict__ hp, const float* __restrict__ dinv,
    const float* __restrict__ b3, const int* __restrict__ row_ptr,
    const int* __restrict__ edge_src,
    __hip_bfloat16* __restrict__ outb, int n_nodes) {
    int node = blockIdx.x * 2 + (threadIdx.x >> 7);
    int c = threadIdx.x & 127;
    if (node >= n_nodes) return;
    int start = row_ptr[node];
    int deg = row_ptr[node + 1] - start;
    float dn = dinv[node];
    float acc = 0.f;
    auto LS = [&](int j) { return edge_src[start + min(j, deg - 1)]; };
    int s0 = LS(0), s1 = LS(1), s2 = LS(2), s3 = LS(3);
    int s4 = LS(4), s5 = LS(5), s6 = LS(6), s7 = LS(7);
    auto HW = [&](int s, int j, float& h, float& w) {
        h = bf2f(hp[(size_t)s * 128 + c]);
        w = (j < deg) ? dinv[s] * dn : 0.f;
    };
    float h0, h1, h2, h3, h4, h5, h6, h7;
    float w0, w1, w2, w3, w4, w5, w6, w7;
    HW(s0, 0, h0, w0); HW(s1, 1, h1, w1); HW(s2, 2, h2, w2); HW(s3, 3, h3, w3);
    HW(s4, 4, h4, w4); HW(s5, 5, h5, w5); HW(s6, 6, h6, w6); HW(s7, 7, h7, w7);
    int j0 = 0;
    while (true) {
        int jn = j0 + 8;
        bool more = jn < deg;
        float g0, g1, g2, g3, g4, g5, g6, g7;
        float v0 = 0.f, v1 = 0.f, v2 = 0.f, v3 = 0.f;
        float v4 = 0.f, v5 = 0.f, v6 = 0.f, v7 = 0.f;
        if (more) {
            int t0 = LS(jn),     t1 = LS(jn + 1), t2 = LS(jn + 2), t3 = LS(jn + 3);
            int t4 = LS(jn + 4), t5 = LS(jn + 5), t6 = LS(jn + 6), t7 = LS(jn + 7);
            HW(t0, jn,     g0, v0); HW(t1, jn + 1, g1, v1);
            HW(t2, jn + 2, g2, v2); HW(t3, jn + 3, g3, v3);
            HW(t4, jn + 4, g4, v4); HW(t5, jn + 5, g5, v5);
            HW(t6, jn + 6, g6, v6); HW(t7, jn + 7, g7, v7);
        }
        acc += w0 * h0 + w1 * h1 + w2 * h2 + w3 * h3
             + w4 * h4 + w5 * h5 + w6 * h6 + w7 * h7;
        if (!more) break;
        h0 = g0; h1 = g1; h2 = g2; h3 = g3;
        h4 = g4; h5 = g5; h6 = g6; h7 = g7;
        w0 = v0; w1 = v1; w2 = v2; w3 = v3;
        w4 = v4; w5 = v5; w6 = v6; w7 = v7;
        j0 = jn;
    }
    outb[(size_t)node * 128 + c] = __float2bfloat16(elu1(acc + b3[c]));
}

// ---------------- pooling ----------------
__global__ void pool1_kernel(const float* __restrict__ Q, const int* __restrict__ batch,
                             float* __restrict__ psum, float* __restrict__ pmax, int n_nodes) {
    int g = blockIdx.x, seg = blockIdx.y;
    int c = threadIdx.x;
    int lo, hi;
    {
        int l = 0, h = n_nodes;
        while (l < h) { int mid = (l + h) >> 1; if (batch[mid] < g) l = mid + 1; else h = mid; }
        lo = l;
        l = lo; h = n_nodes;
        while (l < h) { int mid = (l + h) >> 1; if (batch[mid] < g + 1) l = mid + 1; else h = mid; }
        hi = l;
    }
    int len = hi - lo;
    int a = lo + (int)((long)len * seg / 8);
    int b = lo + (int)((long)len * (seg + 1) / 8);
    float s = 0.f, mx = -INFINITY;
    for (int n = a; n < b; n++) {
        float v = Q[(size_t)n * 128 + c];
        s += v;
        mx = fmaxf(mx, v);
    }
    psum[(g * 8 + seg) * 128 + c] = s;
    pmax[(g * 8 + seg) * 128 + c] = mx;
}

__global__ void pool2_kernel(const float* __restrict__ psum, const float* __restrict__ pmax,
                             const int* __restrict__ batch,
                             const float* __restrict__ bn1g, const float* __restrict__ bn1b,
                             float* __restrict__ hc, int n_nodes) {
    int g = blockIdx.x;
    int c = threadIdx.x;
    int lo, hi;
    {
        int l = 0, h = n_nodes;
        while (l < h) { int mid = (l + h) >> 1; if (batch[mid] < g) l = mid + 1; else h = mid; }
        lo = l;
        l = lo; h = n_nodes;
        while (l < h) { int mid = (l + h) >> 1; if (batch[mid] < g + 1) l = mid + 1; else h = mid; }
        hi = l;
    }
    int cnt = hi - lo;
    float s = 0.f, mx = -INFINITY;
    for (int seg = 0; seg < 8; seg++) {
        s += psum[(g * 8 + seg) * 128 + c];
        mx = fmaxf(mx, pmax[(g * 8 + seg) * 128 + c]);
    }
    float hm = s / fmaxf((float)cnt, 1.f);
    float hx = (cnt > 0 && isfinite(mx)) ? mx : 0.f;
    const float bn_s = 0.99999500003749968f;
    hc[g * 256 + c]       = hm * bn_s * bn1g[c] + bn1b[c];
    hc[g * 256 + 128 + c] = hx * bn_s * bn1g[128 + c] + bn1b[128 + c];
}

__global__ void head_kernel(const float* __restrict__ hc,
                            const float* __restrict__ fc1w, const float* __restrict__ fc1b,
                            const float* __restrict__ bn2g, const float* __restrict__ bn2b,
                            const float* __restrict__ fc2w, const float* __restrict__ fc2b,
                            float* __restrict__ out) {
    int g = blockIdx.x;
    int j = threadIdx.x;
    const float bn_s = 0.99999500003749968f;
    float acc = fc1b[j];
    for (int i = 0; i < 256; i++) acc += hc[g * 256 + i] * fc1w[i * 64 + j];
    acc = elu1(acc);
    acc = acc * bn_s * bn2g[j] + bn2b[j];
    __shared__ float sv[64];
    sv[j] = acc;
    __syncthreads();
    if (j < 2) {
        float o = fc2b[j];
        for (int i = 0; i < 64; i++) o += sv[i] * fc2w[i * 2 + j];
        out[g * 2 + j] = o;
    }
}

// ---------------- launch ----------------
extern "C" void kernel_launch(void* const* d_in, const int* in_sizes, int n_in,
                              void* d_out, int out_size, void* d_ws, size_t ws_size,
                              hipStream_t stream) {
    const float* x    = (const float*)d_in[0];
    const int*   ei   = (const int*)d_in[1];
    const int*   batch= (const int*)d_in[2];
    const float* W1   = (const float*)d_in[3];
    const float* as1  = (const float*)d_in[4];
    const float* ad1  = (const float*)d_in[5];
    const float* b1   = (const float*)d_in[6];
    const float* W2   = (const float*)d_in[7];
    const float* as2  = (const float*)d_in[8];
    const float* ad2  = (const float*)d_in[9];
    const float* b2   = (const float*)d_in[10];
    const float* W3   = (const float*)d_in[11];
    const float* b3   = (const float*)d_in[12];
    const float* wv   = (const float*)d_in[17];
    const float* bv   = (const float*)d_in[18];
    const float* wo   = (const float*)d_in[19];
    const float* bo   = (const float*)d_in[20];
    const float* ln1g = (const float*)d_in[21];
    const float* ln1b = (const float*)d_in[22];
    const float* ln2g = (const float*)d_in[23];
    const float* ln2b = (const float*)d_in[24];
    const float* wf1  = (const float*)d_in[25];
    const float* bf1  = (const float*)d_in[26];
    const float* wf2  = (const float*)d_in[27];
    const float* bf2  = (const float*)d_in[28];
    const float* bn1g = (const float*)d_in[29];
    const float* bn1b = (const float*)d_in[30];
    const float* fc1w = (const float*)d_in[31];
    const float* fc1b = (const float*)d_in[32];
    const float* bn2g = (const float*)d_in[33];
    const float* bn2b = (const float*)d_in[34];
    const float* fc2w = (const float*)d_in[35];
    const float* fc2b = (const float*)d_in[36];
    float* out = (float*)d_out;

    // ---- workspace layout (bytes), peak ~227 MB ----
    char* wsb = (char*)d_ws;
    short* xb    = (short*)wsb;                        // [N,128] bf16
    float* exAf  = (float*)wsb;                        // [H][ET] (xb dead)
    float* exSf  = (float*)(wsb + 8000000);            // [H][NN]
    short* h1t   = (short*)(wsb + 12800000);           // [32][N][32] tile-major
    short* h2t   = (short*)(wsb + 12800000);           // [16][N][32] (h1t dead)
    short* h3pre = (short*)(wsb + 12800000);           // [N,128] row-major (h2t dead)
    short* bh1   = (short*)(wsb + 115200000);          // [32][N][32] tile-major
    short* bh2   = (short*)(wsb + 115200000);          // [16][N][32] (bh1 dead)
    float* fQ    = (float*)(wsb + 128000000);          // [N,128] fp32 (final state)
    short* Qb    = (short*)(wsb + 153600000);          // [N,128] bf16 transformer in
    char* tail = wsb + 217600000;
    short* W1p  = (short*)tail;  tail += 262144;       // 128x1024
    short* W2p  = (short*)tail;  tail += 1048576;      // 1024x512
    short* W3p  = (short*)tail;  tail += 131072;       // 512x128
    short* Wvop = (short*)tail;  tail += 196608;       // 6 x 128x128
    short* wf1p = (short*)tail;  tail += 786432;       // 6 x 128x512
    short* wf2p = (short*)tail;  tail += 786432;       // 6 x 512x128
    float* Wvo  = (float*)tail;  tail += 393216;       // 6 x 128x128 fp32
    float* bvo  = (float*)tail;  tail += 3072;         // 6 x 128 fp32
    float* fAS  = (float*)tail;  tail += 1600000;      // [N,8]
    float* fAD  = (float*)tail;  tail += 1600000;      // [N,8]
    float* fDv  = (float*)tail;  tail += 200000;
    float* psum = (float*)tail;  tail += 262144;
    float* pmax = (float*)tail;  tail += 262144;
    float* fHC  = (float*)tail;  tail += 65536;
    int* iDeg   = (int*)tail;    tail += 200000;
    int* iRP    = (int*)tail;    tail += 200004;
    int* iCur   = (int*)tail;    tail += 200000;       // also: perm after fill_csr
    int* iES    = (int*)tail;    tail += 1000000;

    hipMemsetAsync(iDeg, 0, NN * sizeof(int), stream);
    hipMemsetAsync(iCur, 0, NN * sizeof(int), stream);

    count_deg_kernel<<<(ET + 255) / 256, 256, 0, stream>>>(ei, iDeg);
    scan_kernel<<<1, 1024, 0, stream>>>(iDeg, iRP, NN);
    fill_csr_kernel<<<(ET + 255) / 256, 256, 0, stream>>>(ei, iRP, iCur, iES);
    dinv_kernel<<<(NN + 255) / 256, 256, 0, stream>>>(iRP, fDv);
    int* perm = iCur;   // dead after fill_csr
    local_sort_kernel<<<(NN / 64 + 4) / 4, 256, 0, stream>>>(iRP, perm, NN);

    wvwo_kernel<<<dim3(64, 6), 256, 0, stream>>>(wv, wo, bv, bo, Wvo, bvo);
    auto bprep = [&](const float* B, short* Bp, int K, int N, int ldb, long sStride, int layers) {
        int total = (K >> 5) * (N >> 4) * 64;
        dim3 grid((total + 255) / 256, layers);
        bprep_kernel<<<grid, 256, 0, stream>>>(B, Bp, K, N, ldb, sStride);
    };
    bprep(W1, W1p, 128, 1024, 1024, 0, 1);
    bprep(W2, W2p, 1024, 512, 512, 0, 1);
    bprep(W3, W3p, 512, 128, 128, 0, 1);
    bprep(Wvo, Wvop, 128, 128, 128, 16384, 6);
    bprep(wf1, wf1p, 128, 512, 512, 65536, 6);
    bprep(wf2, wf2p, 512, 128, 128, 65536, 6);
    cast_bf16_kernel<<<(NN * 128 / 4 + 255) / 256, 256, 0, stream>>>(x, xb, NN * 128 / 4);

    const int MB64 = (NN + 63) / 64;                   // 782
    const int MBp = ((MB64 + 7) / 8) * 8;              // 784
    const int NB = (NN + 63) / 64;                     // 782

    // ---- GAT layer 1 ----
    gemm_bf16_kernel<2, false, true, 8, 4, true, false><<<MBp * 8, 256, 0, stream>>>(
        xb, W1p, nullptr, h1t, as1, ad1, fAS, fAD, 8, NN, 128, 1024);
    gat_alpha_kernel<8><<<(NN + 3) / 4, 256, 0, stream>>>(
        fAS, fAD, iRP, iES, exAf, exSf, NN);
    gat_agg_tiled_kernel<<<4 * NB * 8, 256, 0, stream>>>(
        (const ushortT*)h1t, exAf, exSf, b1, iRP, iES, perm, (__hip_bfloat16*)bh1, NN, NB);
    // ---- GAT layer 2 ----
    gemm_bf16_kernel<2, false, true, 4, 0, true, true><<<MBp * 4, 256, 0, stream>>>(
        bh1, W2p, nullptr, h2t, as2, ad2, fAS, fAD, 4, NN, 1024, 512);
    gat_alpha_kernel<4><<<(NN + 3) / 4, 256, 0, stream>>>(
        fAS, fAD, iRP, iES, exAf, exSf, NN);
    gat_agg_tiled_kernel<<<2 * NB * 8, 256, 0, stream>>>(
        (const ushortT*)h2t, exAf, exSf, b2, iRP, iES, perm, (__hip_bfloat16*)bh2, NN, NB);
    // ---- GCN ----
    gemm_bf16_kernel<0, false, true, 1, 0, false, true><<<MBp, 256, 0, stream>>>(
        bh2, W3p, nullptr, h3pre, nullptr, nullptr, nullptr, nullptr, 0, NN, 512, 128);
    gcn_agg_kernel<<<(NN + 1) / 2, 256, 0, stream>>>(
        (const ushortT*)h3pre, fDv, b3, iRP, iES, (__hip_bfloat16*)Qb, NN);
    // ---- Transformer: all 6 layers in ONE barrier-free kernel ----
    transformer_fused_kernel<<<MBp, 256, 0, stream>>>(
        Qb, Wvop, bvo, wf1p, wf2p, bf1, bf2, ln1g, ln1b, ln2g, ln2b, fQ, NN);
    // ---- pool + head ----
    pool1_kernel<<<dim3(GG, 8), 128, 0, stream>>>(fQ, batch, psum, pmax, NN);
    pool2_kernel<<<GG, 128, 0, stream>>>(psum, pmax, batch, bn1g, bn1b, fHC, NN);
    head_kernel<<<GG, 64, 0, stream>>>(fHC, fc1w, fc1b, bn2g, bn2b, fc2w, fc2b, out);
}

// Round 15
// 1114.687 us; speedup vs baseline: 1.2314x; 1.2314x over previous
//
#include <hip/hip_runtime.h>
#include <hip/hip_bf16.h>
#include <math.h>

#define NN 50000
#define EE 200000
#define ET 250000   // EE + NN self loops
#define GG 64
#define LL 6

using short8 = __attribute__((ext_vector_type(8))) short;
using f32x4  = __attribute__((ext_vector_type(4))) float;
typedef unsigned short ushortT;

__device__ __forceinline__ float elu1(float x) { return x > 0.f ? x : expm1f(x); }
__device__ __forceinline__ float gelu_exact(float x) {
    return 0.5f * x * (1.f + erff(x * 0.70710678118654752440f));
}
__device__ __forceinline__ short f2bf(float f) {
    __hip_bfloat16 h = __float2bfloat16(f);
    return *reinterpret_cast<short*>(&h);
}
__device__ __forceinline__ float bf2f(ushortT u) {
    return __uint_as_float(((unsigned)u) << 16);
}
__device__ __forceinline__ void accum8(float* acc, float a, uint4 d) {
    acc[0] += a * bf2f((ushortT)(d.x & 0xffff));
    acc[1] += a * bf2f((ushortT)(d.x >> 16));
    acc[2] += a * bf2f((ushortT)(d.y & 0xffff));
    acc[3] += a * bf2f((ushortT)(d.y >> 16));
    acc[4] += a * bf2f((ushortT)(d.z & 0xffff));
    acc[5] += a * bf2f((ushortT)(d.z >> 16));
    acc[6] += a * bf2f((ushortT)(d.w & 0xffff));
    acc[7] += a * bf2f((ushortT)(d.w >> 16));
}

// ---------------- CSR build ----------------
__global__ void count_deg_kernel(const int* __restrict__ ei, int* __restrict__ deg) {
    int e = blockIdx.x * 256 + threadIdx.x;
    if (e >= ET) return;
    int dst = (e < EE) ? ei[EE + e] : (e - EE);
    atomicAdd(&deg[dst], 1);
}

__global__ void scan_kernel(const int* __restrict__ deg, int* __restrict__ row_ptr, int n) {
    __shared__ int s[1024];
    int tid = threadIdx.x;
    const int per = (n + 1023) / 1024;
    int lo = tid * per, hi = min(lo + per, n);
    int sum = 0;
    for (int i = lo; i < hi; i++) sum += deg[i];
    s[tid] = sum;
    __syncthreads();
    for (int off = 1; off < 1024; off <<= 1) {
        int t = (tid >= off) ? s[tid - off] : 0;
        __syncthreads();
        s[tid] += t;
        __syncthreads();
    }
    int run = s[tid] - sum;
    for (int i = lo; i < hi; i++) { row_ptr[i] = run; run += deg[i]; }
    if (tid == 1023) row_ptr[n] = s[1023];
}

__global__ void fill_csr_kernel(const int* __restrict__ ei, const int* __restrict__ row_ptr,
                                int* __restrict__ cursor, int* __restrict__ edge_src) {
    int e = blockIdx.x * 256 + threadIdx.x;
    if (e >= ET) return;
    int src, dst;
    if (e < EE) { src = ei[e]; dst = ei[EE + e]; }
    else        { src = e - EE; dst = e - EE; }
    int pos = atomicAdd(&cursor[dst], 1);
    edge_src[row_ptr[dst] + pos] = src;
}

__global__ void dinv_kernel(const int* __restrict__ row_ptr, float* __restrict__ dinv) {
    int n = blockIdx.x * 256 + threadIdx.x;
    if (n >= NN) return;
    int d = row_ptr[n + 1] - row_ptr[n];
    dinv[n] = (d > 0) ? rsqrtf((float)d) : 0.f;
}

// ---- BLOCK-LOCAL degree sort (64-node windows) ----------------------------
// R8 WIN: agg 134->124us, FETCH 155MB (R4-level locality + deg-uniform waves).
__global__ __launch_bounds__(256) void local_sort_kernel(
    const int* __restrict__ row_ptr, int* __restrict__ perm, int n_nodes) {
    int g = blockIdx.x * 4 + (threadIdx.x >> 6);
    int l = threadIdx.x & 63;
    int node = g * 64 + l;
    if (g * 64 >= n_nodes) return;
    int d = (node < n_nodes) ? (row_ptr[node + 1] - row_ptr[node]) : 0x7fffffff;
    int rank = 0;
#pragma unroll 16
    for (int j = 0; j < 64; j++) {
        int dj = __shfl(d, j);
        rank += (dj < d) || (dj == d && j < l);
    }
    if (node < n_nodes) perm[g * 64 + rank] = node;
}

// ---- fold wv into wo: Wvo = wv@wo, bvo = bv@wo + bo (fp32, exact) ----
__global__ void wvwo_kernel(const float* __restrict__ wv, const float* __restrict__ wo,
                            const float* __restrict__ bv, const float* __restrict__ bo,
                            float* __restrict__ Wvo, float* __restrict__ bvo) {
    int l = blockIdx.y;
    const float* Wv = wv + l * 16384;
    const float* Wo = wo + l * 16384;
    int tid = blockIdx.x * 256 + threadIdx.x;
    if (tid < 16384) {
        int r = tid >> 7, c = tid & 127;
        float s = 0.f;
        for (int k = 0; k < 128; k++) s += Wv[r * 128 + k] * Wo[k * 128 + c];
        Wvo[l * 16384 + tid] = s;
    }
    if (blockIdx.x == 0 && threadIdx.x < 128) {
        int c = threadIdx.x;
        float s = bo[l * 128 + c];
        for (int k = 0; k < 128; k++) s += bv[l * 128 + k] * Wo[k * 128 + c];
        bvo[l * 128 + c] = s;
    }
}

// ---- weight prep: fp32 [K,N] (ldb) -> bf16 MFMA B-fragment order ----
__global__ void bprep_kernel(const float* __restrict__ B, short* __restrict__ Bp,
                             int K, int N, int ldb, long srcStride) {
    int layer = blockIdx.y;
    const float* Bsrc = B + srcStride * layer;
    short* Bd = Bp + (size_t)K * N * layer;
    int total = (K >> 5) * (N >> 4) * 64;
    int tid = blockIdx.x * 256 + threadIdx.x;
    if (tid >= total) return;
    int l = tid & 63;
    int rest = tid >> 6;
    int kbc = K >> 5;
    int kb = rest % kbc;
    int c16 = rest / kbc;
    int n = c16 * 16 + (l & 15);
    int kbase = kb * 32 + (l >> 4) * 8;
    short v[8];
#pragma unroll
    for (int j = 0; j < 8; j++) v[j] = f2bf(Bsrc[(size_t)(kbase + j) * ldb + n]);
    *(uint4*)(Bd + (size_t)tid * 8) = *(uint4*)v;
}

__global__ void cast_bf16_kernel(const float* __restrict__ in, short* __restrict__ out, int n4) {
    int i = blockIdx.x * 256 + threadIdx.x;
    if (i >= n4) return;
    float4 v = *(const float4*)(in + (size_t)i * 4);
    short s[4] = { f2bf(v.x), f2bf(v.y), f2bf(v.z), f2bf(v.w) };
    *(uint2*)(out + (size_t)i * 4) = *(uint2*)s;
}

// ---------------- MFMA GEMM, LDS B-staging, XCD-aware column-fast split -----
// TMAJ: store bf16 C tile-major [col/32][row][32]. ATILE32: A tile-major.
// EPI: 0 plain, 2 asad + store
template <int EPI, bool BIAS, bool OUTBF16, int NSPLIT, int KBC,
          bool TMAJ = false, bool ATILE32 = false>
__global__ __launch_bounds__(256) void gemm_bf16_kernel(
    const short* __restrict__ A, const short* __restrict__ Bp,
    const float* __restrict__ bias, void* __restrict__ Cv,
    const float* __restrict__ a_s, const float* __restrict__ a_d,
    float* __restrict__ as_out, float* __restrict__ ad_out, int asH,
    int M, int K, int Nc) {
    __shared__ short Bs[(KBC > 0) ? KBC * 4096 : 8192];
    int t = threadIdx.x;
    int w = t >> 6, l = t & 63;
    int ln = l & 15, lq = l >> 4;
    int MBceil = (M + 63) >> 6;
    int bx = blockIdx.x;
    int xcd = bx & 7, idx = bx >> 3;
    int t2 = idx % NSPLIT;
    int mb = (idx / NSPLIT) * 8 + xcd;
    if (mb >= MBceil) return;
    int bm = mb * 64 + w * 16;
    int arow = bm + ln;
    bool aok = arow < M;
    int rowb = bm + lq * 4;
    const short* Ap = A + (size_t)arow * K + lq * 8;

    auto aload = [&](int kb) -> short8 {
        if (!aok) return (short8){0, 0, 0, 0, 0, 0, 0, 0};
        const short* p;
        if constexpr (ATILE32)
            p = A + ((size_t)kb * M + arow) * 32 + lq * 8;
        else
            p = Ap + kb * 32;
        return *(const short8*)p;
    };

    f32x4 acc[8];
#pragma unroll
    for (int j = 0; j < 8; j++) acc[j] = (f32x4){0.f, 0.f, 0.f, 0.f};

    if constexpr (KBC > 0) {
        {
            const uint4* src = (const uint4*)(Bp + (size_t)t2 * KBC * 4096);
            uint4* dst = (uint4*)Bs;
#pragma unroll
            for (int i = 0; i < KBC * 2; i++)
                dst[i * 256 + t] = src[i * 256 + t];
        }
        short8 af[KBC];
#pragma unroll
        for (int kb = 0; kb < KBC; kb++)
            af[kb] = aload(kb);
        __syncthreads();
#pragma unroll
        for (int kb = 0; kb < KBC; kb++)
#pragma unroll
            for (int ct = 0; ct < 8; ct++) {
                short8 bfr = *(const short8*)(Bs + ((ct * KBC + kb) * 64 + l) * 8);
                acc[ct] = __builtin_amdgcn_mfma_f32_16x16x32_bf16(af[kb], bfr, acc[ct], 0, 0, 0);
            }
    } else {
        int kbc = K >> 5;
        int sct = t >> 5, spart = t & 31;
        auto stage = [&](int buf, int kb) {
            const uint4* src = (const uint4*)(Bp + ((size_t)(t2 * 8 + sct) * kbc + kb) * 512);
            uint4* dst = (uint4*)(Bs + buf * 4096 + sct * 512);
            dst[spart * 2]     = src[spart * 2];
            dst[spart * 2 + 1] = src[spart * 2 + 1];
        };
        stage(0, 0);
        __syncthreads();
        for (int kb = 0; kb < kbc; kb++) {
            if (kb + 1 < kbc) stage((kb + 1) & 1, kb + 1);
            short8 af = aload(kb);
            const short* bsb = Bs + (kb & 1) * 4096;
#pragma unroll
            for (int ct = 0; ct < 8; ct++) {
                short8 bfr = *(const short8*)(bsb + (ct * 64 + l) * 8);
                acc[ct] = __builtin_amdgcn_mfma_f32_16x16x32_bf16(af, bfr, acc[ct], 0, 0, 0);
            }
            __syncthreads();
        }
    }

    if (EPI == 2) {
        const float* asv = a_s + t2 * 128;
        const float* adv = a_d + t2 * 128;
#pragma unroll
        for (int reg = 0; reg < 4; reg++) {
            float vs = 0.f, vd = 0.f;
#pragma unroll
            for (int ct = 0; ct < 8; ct++) {
                int colL = ct * 16 + ln;
                float av = acc[ct][reg];
                vs += av * asv[colL];
                vd += av * adv[colL];
            }
            vs += __shfl_xor(vs, 1); vs += __shfl_xor(vs, 2);
            vs += __shfl_xor(vs, 4); vs += __shfl_xor(vs, 8);
            vd += __shfl_xor(vd, 1); vd += __shfl_xor(vd, 2);
            vd += __shfl_xor(vd, 4); vd += __shfl_xor(vd, 8);
            int row = rowb + reg;
            if (ln == 0 && row < M) {
                as_out[(size_t)row * asH + t2] = vs;
                ad_out[(size_t)row * asH + t2] = vd;
            }
        }
    }
#pragma unroll
    for (int ct = 0; ct < 8; ct++) {
        int col = t2 * 128 + ct * 16 + ln;
        float bv_ = BIAS ? bias[col] : 0.f;
#pragma unroll
        for (int reg = 0; reg < 4; reg++) {
            int row = rowb + reg;
            if (row < M) {
                float v = acc[ct][reg] + bv_;
                if (OUTBF16) {
                    size_t addr;
                    if constexpr (TMAJ)
                        addr = ((size_t)(col >> 5) * M + row) * 32 + (col & 31);
                    else
                        addr = (size_t)row * Nc + col;
                    ((__hip_bfloat16*)Cv)[addr] = __float2bfloat16(v);
                } else {
                    ((float*)Cv)[(size_t)row * Nc + col] = v;
                }
            }
        }
    }
}

// ---- fully fused 6-layer transformer (R10 configuration, RESTORED) --------
// A/B record across R10-R14: {LDS 50K + 108 barriers + VGPR 124} = 386us is
// the constrained optimum of this kernel family. Escape routes eliminated:
// R11 wave-pin -> spills (462); R12 LDS-swizzle -> VGPR 132 cliff (637);
// R13 half-Bs -> 2x barriers, grid caps co-residency at 3.06 blk/CU so the
// freed LDS is unusable (463); R14 barrier-free L2-direct -> load-latency
// serialization at VGPR 104 (665). Grid cap (784 blocks / 256 CU) makes
// occupancy-oriented tuning a dead end; the 386us is structural.
#define TS 136
__global__ __launch_bounds__(256) void transformer_fused_kernel(
    const short* __restrict__ Qb, const short* __restrict__ Wvop,
    const float* __restrict__ bvo, const short* __restrict__ wf1p,
    const short* __restrict__ wf2p, const float* __restrict__ bf1,
    const float* __restrict__ bf2, const float* __restrict__ ln1g,
    const float* __restrict__ ln1b, const float* __restrict__ ln2g,
    const float* __restrict__ ln2b, float* __restrict__ fQ, int M) {
    __shared__ short Bs[16384];          // 32 KB weight stage
    __shared__ short Ts[4][16 * TS];     // per-wave T bounce, stride 136
    int t = threadIdx.x;
    int w = t >> 6, l = t & 63;
    int ln = l & 15, lq = l >> 4;
    int MBceil = (M + 63) >> 6;
    int bx = blockIdx.x;
    int xcd = bx & 7, mb = (bx >> 3) * 8 + xcd;
    if (mb >= MBceil) return;
    int bm = mb * 64 + w * 16;
    int rowb = bm + lq * 4;
    short* Tw = &Ts[w][0];

    // load state as C-fragments (col=ct*16+ln, row=rowb+reg)
    ushortT hc[8][4];
#pragma unroll
    for (int ct = 0; ct < 8; ct++) {
        int col = ct * 16 + ln;
#pragma unroll
        for (int reg = 0; reg < 4; reg++) {
            int row = rowb + reg;
            hc[ct][reg] = (row < M) ? ((const ushortT*)Qb)[(size_t)row * 128 + col] : 0;
        }
    }

    // bounce hc (C-frag) -> A-frags via wave-private LDS tile
    auto bounceA = [&](short8* a) {
#pragma unroll
        for (int ct = 0; ct < 8; ct++)
#pragma unroll
            for (int reg = 0; reg < 4; reg++)
                Tw[(lq * 4 + reg) * TS + ct * 16 + ln] = (short)hc[ct][reg];
#pragma unroll
        for (int kb = 0; kb < 4; kb++)
            a[kb] = *(const short8*)(Tw + ln * TS + kb * 32 + lq * 8);
    };
    // residual + bias + LayerNorm over 128 cols; updates hc (bf16-rounded)
    auto lnEpi = [&](f32x4* acc, const float* bias, const float* g,
                     const float* b, bool writeF) {
        float v[8][4];
#pragma unroll
        for (int ct = 0; ct < 8; ct++) {
            float bv_ = bias[ct * 16 + ln];
#pragma unroll
            for (int reg = 0; reg < 4; reg++)
                v[ct][reg] = acc[ct][reg] + bv_ + bf2f(hc[ct][reg]);
        }
#pragma unroll
        for (int reg = 0; reg < 4; reg++) {
            float s = 0.f;
#pragma unroll
            for (int ct = 0; ct < 8; ct++) s += v[ct][reg];
            s += __shfl_xor(s, 1); s += __shfl_xor(s, 2);
            s += __shfl_xor(s, 4); s += __shfl_xor(s, 8);
            float mean = s * (1.f / 128.f);
            float s2 = 0.f;
#pragma unroll
            for (int ct = 0; ct < 8; ct++) { float d = v[ct][reg] - mean; s2 += d * d; }
            s2 += __shfl_xor(s2, 1); s2 += __shfl_xor(s2, 2);
            s2 += __shfl_xor(s2, 4); s2 += __shfl_xor(s2, 8);
            float rstd = rsqrtf(s2 * (1.f / 128.f) + 1e-5f);
            int row = rowb + reg;
#pragma unroll
            for (int ct = 0; ct < 8; ct++) {
                int col = ct * 16 + ln;
                float o = (v[ct][reg] - mean) * rstd * g[col] + b[col];
                hc[ct][reg] = (ushortT)f2bf(o);
                if (writeF && row < M) fQ[(size_t)row * 128 + col] = o;
            }
        }
    };

    for (int lay = 0; lay < LL; lay++) {
        // ---------- g1: acc = h @ Wvo ----------
        short8 a1[4];
        bounceA(a1);
        __syncthreads();                 // prev-iter Bs reads complete
        {
            const uint4* src = (const uint4*)(Wvop + (size_t)lay * 16384);
            uint4* dst = (uint4*)Bs;
#pragma unroll
            for (int i = 0; i < 8; i++) dst[i * 256 + t] = src[i * 256 + t];
        }
        __syncthreads();
        f32x4 acc1[8];
#pragma unroll
        for (int j = 0; j < 8; j++) acc1[j] = (f32x4){0.f, 0.f, 0.f, 0.f};
#pragma unroll
        for (int kb = 0; kb < 4; kb++)
#pragma unroll
            for (int ct = 0; ct < 8; ct++) {
                short8 bfr = *(const short8*)(Bs + ((ct * 4 + kb) * 64 + l) * 8);
                acc1[ct] = __builtin_amdgcn_mfma_f32_16x16x32_bf16(a1[kb], bfr, acc1[ct], 0, 0, 0);
            }
        lnEpi(acc1, bvo + lay * 128, ln1g + lay * 128, ln1b + lay * 128, false);

        // ---------- FF: acc2 = gelu(h@wf1+b1) @ wf2 ----------
        short8 af1[4];
        bounceA(af1);
        const short* w1l = wf1p + (size_t)lay * 65536;
        const short* w2l = wf2p + (size_t)lay * 65536;
        f32x4 acc2[8];
#pragma unroll
        for (int j = 0; j < 8; j++) acc2[j] = (f32x4){0.f, 0.f, 0.f, 0.f};
        for (int kc = 0; kc < 4; kc++) {
            __syncthreads();             // prior Bs reads complete
            {
                const uint4* src = (const uint4*)(w1l + kc * 16384);
                uint4* dst = (uint4*)Bs;
#pragma unroll
                for (int i = 0; i < 8; i++) dst[i * 256 + t] = src[i * 256 + t];
            }
            __syncthreads();
            f32x4 acct[8];
#pragma unroll
            for (int j = 0; j < 8; j++) acct[j] = (f32x4){0.f, 0.f, 0.f, 0.f};
#pragma unroll
            for (int kb = 0; kb < 4; kb++)
#pragma unroll
                for (int ct = 0; ct < 8; ct++) {
                    short8 bfr = *(const short8*)(Bs + ((ct * 4 + kb) * 64 + l) * 8);
                    acct[ct] = __builtin_amdgcn_mfma_f32_16x16x32_bf16(af1[kb], bfr, acct[ct], 0, 0, 0);
                }
            // gelu + bias -> wave-private T (bf16) -> A2 frags
            const float* bfc = bf1 + lay * 512 + kc * 128;
#pragma unroll
            for (int ct = 0; ct < 8; ct++) {
                float bv = bfc[ct * 16 + ln];
#pragma unroll
                for (int reg = 0; reg < 4; reg++)
                    Tw[(lq * 4 + reg) * TS + ct * 16 + ln] = f2bf(gelu_exact(acct[ct][reg] + bv));
            }
            short8 a2[4];
#pragma unroll
            for (int kb2 = 0; kb2 < 4; kb2++)
                a2[kb2] = *(const short8*)(Tw + ln * TS + kb2 * 32 + lq * 8);
            __syncthreads();             // all waves' MFMA1 Bs reads done
            {
                int sct = t >> 5, spart = t & 31;
                const uint4* src = (const uint4*)(w2l + (size_t)(sct * 16 + kc * 4) * 512);
                uint4* dst = (uint4*)Bs + sct * 256;
#pragma unroll
                for (int j = 0; j < 8; j++) dst[spart + j * 32] = src[spart + j * 32];
            }
            __syncthreads();
#pragma unroll
            for (int kb2 = 0; kb2 < 4; kb2++)
#pragma unroll
                for (int ct = 0; ct < 8; ct++) {
                    short8 bfr = *(const short8*)(Bs + ((ct * 4 + kb2) * 64 + l) * 8);
                    acc2[ct] = __builtin_amdgcn_mfma_f32_16x16x32_bf16(a2[kb2], bfr, acc2[ct], 0, 0, 0);
                }
        }
        lnEpi(acc2, bf2 + lay * 128, ln2g + lay * 128, ln2b + lay * 128, lay == LL - 1);
    }
}

// ---- GAT softmax phase: exact 2-pass per (node, head), 1 wave/node --------
template <int H>
__global__ __launch_bounds__(256) void gat_alpha_kernel(
    const float* __restrict__ as_, const float* __restrict__ ad_,
    const int* __restrict__ row_ptr, const int* __restrict__ edge_src,
    float* __restrict__ exA, float* __restrict__ exS, int n_nodes) {
    const int GS = 64 / H;
    int node = blockIdx.x * 4 + (threadIdx.x >> 6);
    if (node >= n_nodes) return;
    int l = threadIdx.x & 63;
    int h = l / GS;
    int lig = l % GS;
    int start = row_ptr[node];
    int deg = row_ptr[node + 1] - start;
    float adn = ad_[(size_t)node * H + h];
    float m = -1e30f;
    for (int j = lig; j < deg; j += GS) {
        int s = edge_src[start + j];
        float e = as_[(size_t)s * H + h] + adn;
        e = e > 0.f ? e : 0.2f * e;
        m = fmaxf(m, e);
    }
#pragma unroll
    for (int mask = 1; mask < GS; mask <<= 1)
        m = fmaxf(m, __shfl_xor(m, mask));
    float S = 0.f;
    for (int j = lig; j < deg; j += GS) {
        int s = edge_src[start + j];
        float e = as_[(size_t)s * H + h] + adn;
        e = e > 0.f ? e : 0.2f * e;
        float ex = expf(e - m);
        exA[(size_t)h * ET + (start + j)] = ex;
        S += ex;
    }
#pragma unroll
    for (int mask = 1; mask < GS; mask <<= 1)
        S += __shfl_xor(S, mask);
    if (lig == 0) exS[(size_t)h * n_nodes + node] = S;
}

// ---- tiled GAT aggregation: 32-col tiles, XCD-pinned, local-deg-sorted ----
__global__ __launch_bounds__(256) void gat_agg_tiled_kernel(
    const ushortT* __restrict__ hT, const float* __restrict__ exA,
    const float* __restrict__ exS, const float* __restrict__ bias,
    const int* __restrict__ row_ptr, const int* __restrict__ edge_src,
    const int* __restrict__ perm,
    __hip_bfloat16* __restrict__ outT, int n_nodes, int NB) {
    int bx = blockIdx.x;
    int xcd = bx & 7, rest = bx >> 3;
    int tl = rest / NB, nb = rest - tl * NB;
    int tile = tl * 8 + xcd;
    int nl = threadIdx.x >> 2, q = threadIdx.x & 3;
    int idx = nb * 64 + nl;
    if (idx >= n_nodes) return;
    int node = perm[idx];
    int hb = tile >> 2;
    const ushortT* __restrict__ base = hT + (size_t)tile * n_nodes * 32 + q * 8;
    const float* __restrict__ exAh = exA + (size_t)hb * ET;
    int start = row_ptr[node];
    int deg = row_ptr[node + 1] - start;
    float acc[8];
#pragma unroll
    for (int c = 0; c < 8; c++) acc[c] = 0.f;
    for (int j = 0; j < deg; j++) {
        int s = edge_src[start + j];
        float a = exAh[start + j];
        uint4 d = *(const uint4*)(base + (size_t)s * 32);
        accum8(acc, a, d);
    }
    float inv = 1.f / (exS[(size_t)hb * n_nodes + node] + 1e-16f);
    const float* bp = bias + tile * 32 + q * 8;
    short o[8];
#pragma unroll
    for (int c = 0; c < 8; c++)
        o[c] = f2bf(elu1(acc[c] * inv + bp[c]));
    *(uint4*)(outT + ((size_t)tile * n_nodes + node) * 32 + q * 8) = *(uint4*)o;
}

// ---------------- GCN aggregation (bf16 in, row-major) -> bf16 Qb -----------
__global__ __launch_bounds__(256, 2) void gcn_agg_kernel(
    const ushortT* __restrict__ hp, const float* __restrict__ dinv,
    const float* __restrict__ b3, const int* __restrict__ row_ptr,
    const int* __restrict__ edge_src,
    __hip_bfloat16* __restrict__ outb, int n_nodes) {
    int node = blockIdx.x * 2 + (threadIdx.x >> 7);
    int c = threadIdx.x & 127;
    if (node >= n_nodes) return;
    int start = row_ptr[node];
    int deg = row_ptr[node + 1] - start;
    float dn = dinv[node];
    float acc = 0.f;
    auto LS = [&](int j) { return edge_src[start + min(j, deg - 1)]; };
    int s0 = LS(0), s1 = LS(1), s2 = LS(2), s3 = LS(3);
    int s4 = LS(4), s5 = LS(5), s6 = LS(6), s7 = LS(7);
    auto HW = [&](int s, int j, float& h, float& w) {
        h = bf2f(hp[(size_t)s * 128 + c]);
        w = (j < deg) ? dinv[s] * dn : 0.f;
    };
    float h0, h1, h2, h3, h4, h5, h6, h7;
    float w0, w1, w2, w3, w4, w5, w6, w7;
    HW(s0, 0, h0, w0); HW(s1, 1, h1, w1); HW(s2, 2, h2, w2); HW(s3, 3, h3, w3);
    HW(s4, 4, h4, w4); HW(s5, 5, h5, w5); HW(s6, 6, h6, w6); HW(s7, 7, h7, w7);
    int j0 = 0;
    while (true) {
        int jn = j0 + 8;
        bool more = jn < deg;
        float g0, g1, g2, g3, g4, g5, g6, g7;
        float v0 = 0.f, v1 = 0.f, v2 = 0.f, v3 = 0.f;
        float v4 = 0.f, v5 = 0.f, v6 = 0.f, v7 = 0.f;
        if (more) {
            int t0 = LS(jn),     t1 = LS(jn + 1), t2 = LS(jn + 2), t3 = LS(jn + 3);
            int t4 = LS(jn + 4), t5 = LS(jn + 5), t6 = LS(jn + 6), t7 = LS(jn + 7);
            HW(t0, jn,     g0, v0); HW(t1, jn + 1, g1, v1);
            HW(t2, jn + 2, g2, v2); HW(t3, jn + 3, g3, v3);
            HW(t4, jn + 4, g4, v4); HW(t5, jn + 5, g5, v5);
            HW(t6, jn + 6, g6, v6); HW(t7, jn + 7, g7, v7);
        }
        acc += w0 * h0 + w1 * h1 + w2 * h2 + w3 * h3
             + w4 * h4 + w5 * h5 + w6 * h6 + w7 * h7;
        if (!more) break;
        h0 = g0; h1 = g1; h2 = g2; h3 = g3;
        h4 = g4; h5 = g5; h6 = g6; h7 = g7;
        w0 = v0; w1 = v1; w2 = v2; w3 = v3;
        w4 = v4; w5 = v5; w6 = v6; w7 = v7;
        j0 = jn;
    }
    outb[(size_t)node * 128 + c] = __float2bfloat16(elu1(acc + b3[c]));
}

// ---------------- pooling ----------------
__global__ void pool1_kernel(const float* __restrict__ Q, const int* __restrict__ batch,
                             float* __restrict__ psum, float* __restrict__ pmax, int n_nodes) {
    int g = blockIdx.x, seg = blockIdx.y;
    int c = threadIdx.x;
    int lo, hi;
    {
        int l = 0, h = n_nodes;
        while (l < h) { int mid = (l + h) >> 1; if (batch[mid] < g) l = mid + 1; else h = mid; }
        lo = l;
        l = lo; h = n_nodes;
        while (l < h) { int mid = (l + h) >> 1; if (batch[mid] < g + 1) l = mid + 1; else h = mid; }
        hi = l;
    }
    int len = hi - lo;
    int a = lo + (int)((long)len * seg / 8);
    int b = lo + (int)((long)len * (seg + 1) / 8);
    float s = 0.f, mx = -INFINITY;
    for (int n = a; n < b; n++) {
        float v = Q[(size_t)n * 128 + c];
        s += v;
        mx = fmaxf(mx, v);
    }
    psum[(g * 8 + seg) * 128 + c] = s;
    pmax[(g * 8 + seg) * 128 + c] = mx;
}

__global__ void pool2_kernel(const float* __restrict__ psum, const float* __restrict__ pmax,
                             const int* __restrict__ batch,
                             const float* __restrict__ bn1g, const float* __restrict__ bn1b,
                             float* __restrict__ hc, int n_nodes) {
    int g = blockIdx.x;
    int c = threadIdx.x;
    int lo, hi;
    {
        int l = 0, h = n_nodes;
        while (l < h) { int mid = (l + h) >> 1; if (batch[mid] < g) l = mid + 1; else h = mid; }
        lo = l;
        l = lo; h = n_nodes;
        while (l < h) { int mid = (l + h) >> 1; if (batch[mid] < g + 1) l = mid + 1; else h = mid; }
        hi = l;
    }
    int cnt = hi - lo;
    float s = 0.f, mx = -INFINITY;
    for (int seg = 0; seg < 8; seg++) {
        s += psum[(g * 8 + seg) * 128 + c];
        mx = fmaxf(mx, pmax[(g * 8 + seg) * 128 + c]);
    }
    float hm = s / fmaxf((float)cnt, 1.f);
    float hx = (cnt > 0 && isfinite(mx)) ? mx : 0.f;
    const float bn_s = 0.99999500003749968f;
    hc[g * 256 + c]       = hm * bn_s * bn1g[c] + bn1b[c];
    hc[g * 256 + 128 + c] = hx * bn_s * bn1g[128 + c] + bn1b[128 + c];
}

__global__ void head_kernel(const float* __restrict__ hc,
                            const float* __restrict__ fc1w, const float* __restrict__ fc1b,
                            const float* __restrict__ bn2g, const float* __restrict__ bn2b,
                            const float* __restrict__ fc2w, const float* __restrict__ fc2b,
                            float* __restrict__ out) {
    int g = blockIdx.x;
    int j = threadIdx.x;
    const float bn_s = 0.99999500003749968f;
    float acc = fc1b[j];
    for (int i = 0; i < 256; i++) acc += hc[g * 256 + i] * fc1w[i * 64 + j];
    acc = elu1(acc);
    acc = acc * bn_s * bn2g[j] + bn2b[j];
    __shared__ float sv[64];
    sv[j] = acc;
    __syncthreads();
    if (j < 2) {
        float o = fc2b[j];
        for (int i = 0; i < 64; i++) o += sv[i] * fc2w[i * 2 + j];
        out[g * 2 + j] = o;
    }
}

// ---------------- launch ----------------
extern "C" void kernel_launch(void* const* d_in, const int* in_sizes, int n_in,
                              void* d_out, int out_size, void* d_ws, size_t ws_size,
                              hipStream_t stream) {
    const float* x    = (const float*)d_in[0];
    const int*   ei   = (const int*)d_in[1];
    const int*   batch= (const int*)d_in[2];
    const float* W1   = (const float*)d_in[3];
    const float* as1  = (const float*)d_in[4];
    const float* ad1  = (const float*)d_in[5];
    const float* b1   = (const float*)d_in[6];
    const float* W2   = (const float*)d_in[7];
    const float* as2  = (const float*)d_in[8];
    const float* ad2  = (const float*)d_in[9];
    const float* b2   = (const float*)d_in[10];
    const float* W3   = (const float*)d_in[11];
    const float* b3   = (const float*)d_in[12];
    const float* wv   = (const float*)d_in[17];
    const float* bv   = (const float*)d_in[18];
    const float* wo   = (const float*)d_in[19];
    const float* bo   = (const float*)d_in[20];
    const float* ln1g = (const float*)d_in[21];
    const float* ln1b = (const float*)d_in[22];
    const float* ln2g = (const float*)d_in[23];
    const float* ln2b = (const float*)d_in[24];
    const float* wf1  = (const float*)d_in[25];
    const float* bf1  = (const float*)d_in[26];
    const float* wf2  = (const float*)d_in[27];
    const float* bf2  = (const float*)d_in[28];
    const float* bn1g = (const float*)d_in[29];
    const float* bn1b = (const float*)d_in[30];
    const float* fc1w = (const float*)d_in[31];
    const float* fc1b = (const float*)d_in[32];
    const float* bn2g = (const float*)d_in[33];
    const float* bn2b = (const float*)d_in[34];
    const float* fc2w = (const float*)d_in[35];
    const float* fc2b = (const float*)d_in[36];
    float* out = (float*)d_out;

    // ---- workspace layout (bytes), peak ~227 MB ----
    char* wsb = (char*)d_ws;
    short* xb    = (short*)wsb;                        // [N,128] bf16
    float* exAf  = (float*)wsb;                        // [H][ET] (xb dead)
    float* exSf  = (float*)(wsb + 8000000);            // [H][NN]
    short* h1t   = (short*)(wsb + 12800000);           // [32][N][32] tile-major
    short* h2t   = (short*)(wsb + 12800000);           // [16][N][32] (h1t dead)
    short* h3pre = (short*)(wsb + 12800000);           // [N,128] row-major (h2t dead)
    short* bh1   = (short*)(wsb + 115200000);          // [32][N][32] tile-major
    short* bh2   = (short*)(wsb + 115200000);          // [16][N][32] (bh1 dead)
    float* fQ    = (float*)(wsb + 128000000);          // [N,128] fp32 (final state)
    short* Qb    = (short*)(wsb + 153600000);          // [N,128] bf16 transformer in
    char* tail = wsb + 217600000;
    short* W1p  = (short*)tail;  tail += 262144;       // 128x1024
    short* W2p  = (short*)tail;  tail += 1048576;      // 1024x512
    short* W3p  = (short*)tail;  tail += 131072;       // 512x128
    short* Wvop = (short*)tail;  tail += 196608;       // 6 x 128x128
    short* wf1p = (short*)tail;  tail += 786432;       // 6 x 128x512
    short* wf2p = (short*)tail;  tail += 786432;       // 6 x 512x128
    float* Wvo  = (float*)tail;  tail += 393216;       // 6 x 128x128 fp32
    float* bvo  = (float*)tail;  tail += 3072;         // 6 x 128 fp32
    float* fAS  = (float*)tail;  tail += 1600000;      // [N,8]
    float* fAD  = (float*)tail;  tail += 1600000;      // [N,8]
    float* fDv  = (float*)tail;  tail += 200000;
    float* psum = (float*)tail;  tail += 262144;
    float* pmax = (float*)tail;  tail += 262144;
    float* fHC  = (float*)tail;  tail += 65536;
    int* iDeg   = (int*)tail;    tail += 200000;
    int* iRP    = (int*)tail;    tail += 200004;
    int* iCur   = (int*)tail;    tail += 200000;       // also: perm after fill_csr
    int* iES    = (int*)tail;    tail += 1000000;

    hipMemsetAsync(iDeg, 0, NN * sizeof(int), stream);
    hipMemsetAsync(iCur, 0, NN * sizeof(int), stream);

    count_deg_kernel<<<(ET + 255) / 256, 256, 0, stream>>>(ei, iDeg);
    scan_kernel<<<1, 1024, 0, stream>>>(iDeg, iRP, NN);
    fill_csr_kernel<<<(ET + 255) / 256, 256, 0, stream>>>(ei, iRP, iCur, iES);
    dinv_kernel<<<(NN + 255) / 256, 256, 0, stream>>>(iRP, fDv);
    int* perm = iCur;   // dead after fill_csr
    local_sort_kernel<<<(NN / 64 + 4) / 4, 256, 0, stream>>>(iRP, perm, NN);

    wvwo_kernel<<<dim3(64, 6), 256, 0, stream>>>(wv, wo, bv, bo, Wvo, bvo);
    auto bprep = [&](const float* B, short* Bp, int K, int N, int ldb, long sStride, int layers) {
        int total = (K >> 5) * (N >> 4) * 64;
        dim3 grid((total + 255) / 256, layers);
        bprep_kernel<<<grid, 256, 0, stream>>>(B, Bp, K, N, ldb, sStride);
    };
    bprep(W1, W1p, 128, 1024, 1024, 0, 1);
    bprep(W2, W2p, 1024, 512, 512, 0, 1);
    bprep(W3, W3p, 512, 128, 128, 0, 1);
    bprep(Wvo, Wvop, 128, 128, 128, 16384, 6);
    bprep(wf1, wf1p, 128, 512, 512, 65536, 6);
    bprep(wf2, wf2p, 512, 128, 128, 65536, 6);
    cast_bf16_kernel<<<(NN * 128 / 4 + 255) / 256, 256, 0, stream>>>(x, xb, NN * 128 / 4);

    const int MB64 = (NN + 63) / 64;                   // 782
    const int MBp = ((MB64 + 7) / 8) * 8;              // 784
    const int NB = (NN + 63) / 64;                     // 782

    // ---- GAT layer 1 ----
    gemm_bf16_kernel<2, false, true, 8, 4, true, false><<<MBp * 8, 256, 0, stream>>>(
        xb, W1p, nullptr, h1t, as1, ad1, fAS, fAD, 8, NN, 128, 1024);
    gat_alpha_kernel<8><<<(NN + 3) / 4, 256, 0, stream>>>(
        fAS, fAD, iRP, iES, exAf, exSf, NN);
    gat_agg_tiled_kernel<<<4 * NB * 8, 256, 0, stream>>>(
        (const ushortT*)h1t, exAf, exSf, b1, iRP, iES, perm, (__hip_bfloat16*)bh1, NN, NB);
    // ---- GAT layer 2 ----
    gemm_bf16_kernel<2, false, true, 4, 0, true, true><<<MBp * 4, 256, 0, stream>>>(
        bh1, W2p, nullptr, h2t, as2, ad2, fAS, fAD, 4, NN, 1024, 512);
    gat_alpha_kernel<4><<<(NN + 3) / 4, 256, 0, stream>>>(
        fAS, fAD, iRP, iES, exAf, exSf, NN);
    gat_agg_tiled_kernel<<<2 * NB * 8, 256, 0, stream>>>(
        (const ushortT*)h2t, exAf, exSf, b2, iRP, iES, perm, (__hip_bfloat16*)bh2, NN, NB);
    // ---- GCN ----
    gemm_bf16_kernel<0, false, true, 1, 0, false, true><<<MBp, 256, 0, stream>>>(
        bh2, W3p, nullptr, h3pre, nullptr, nullptr, nullptr, nullptr, 0, NN, 512, 128);
    gcn_agg_kernel<<<(NN + 1) / 2, 256, 0, stream>>>(
        (const ushortT*)h3pre, fDv, b3, iRP, iES, (__hip_bfloat16*)Qb, NN);
    // ---- Transformer: all 6 layers in ONE kernel (R10 configuration) ----
    transformer_fused_kernel<<<MBp, 256, 0, stream>>>(
        Qb, Wvop, bvo, wf1p, wf2p, bf1, bf2, ln1g, ln1b, ln2g, ln2b, fQ, NN);
    // ---- pool + head ----
    pool1_kernel<<<dim3(GG, 8), 128, 0, stream>>>(fQ, batch, psum, pmax, NN);
    pool2_kernel<<<GG, 128, 0, stream>>>(psum, pmax, batch, bn1g, bn1b, fHC, NN);
    head_kernel<<<GG, 64, 0, stream>>>(fHC, fc1w, fc1b, bn2g, bn2b, fc2w, fc2b, out);
}

// Round 16
// 1099.797 us; speedup vs baseline: 1.2480x; 1.0135x over previous
//
#include <hip/hip_runtime.h>
#include <hip/hip_bf16.h>
#include <math.h>

#define NN 50000
#define EE 200000
#define ET 250000   // EE + NN self loops
#define GG 64
#define LL 6

using short8 = __attribute__((ext_vector_type(8))) short;
using f32x4  = __attribute__((ext_vector_type(4))) float;
typedef unsigned short ushortT;

__device__ __forceinline__ float elu1(float x) { return x > 0.f ? x : expm1f(x); }
__device__ __forceinline__ float gelu_exact(float x) {
    return 0.5f * x * (1.f + erff(x * 0.70710678118654752440f));
}
__device__ __forceinline__ short f2bf(float f) {
    __hip_bfloat16 h = __float2bfloat16(f);
    return *reinterpret_cast<short*>(&h);
}
__device__ __forceinline__ float bf2f(ushortT u) {
    return __uint_as_float(((unsigned)u) << 16);
}
__device__ __forceinline__ void accum8(float* acc, float a, uint4 d) {
    acc[0] += a * bf2f((ushortT)(d.x & 0xffff));
    acc[1] += a * bf2f((ushortT)(d.x >> 16));
    acc[2] += a * bf2f((ushortT)(d.y & 0xffff));
    acc[3] += a * bf2f((ushortT)(d.y >> 16));
    acc[4] += a * bf2f((ushortT)(d.z & 0xffff));
    acc[5] += a * bf2f((ushortT)(d.z >> 16));
    acc[6] += a * bf2f((ushortT)(d.w & 0xffff));
    acc[7] += a * bf2f((ushortT)(d.w >> 16));
}

// async global->LDS, 16B per lane. LDS arg must be WAVE-UNIFORM base; HW
// scatters lane l to base + l*16 (guide m97/m104). Zero data VGPRs.
__device__ __forceinline__ void gl16(const short* g, short* l) {
#if defined(__has_builtin) && __has_builtin(__builtin_amdgcn_global_load_lds)
    __builtin_amdgcn_global_load_lds(
        (const __attribute__((address_space(1))) unsigned int*)g,
        (__attribute__((address_space(3))) unsigned int*)l, 16, 0, 0);
#else
    // correctness fallback (synchronous): lane writes its own 16B
    *(uint4*)l = *(const uint4*)g;
#endif
}

// ---------------- CSR build ----------------
__global__ void count_deg_kernel(const int* __restrict__ ei, int* __restrict__ deg) {
    int e = blockIdx.x * 256 + threadIdx.x;
    if (e >= ET) return;
    int dst = (e < EE) ? ei[EE + e] : (e - EE);
    atomicAdd(&deg[dst], 1);
}

__global__ void scan_kernel(const int* __restrict__ deg, int* __restrict__ row_ptr, int n) {
    __shared__ int s[1024];
    int tid = threadIdx.x;
    const int per = (n + 1023) / 1024;
    int lo = tid * per, hi = min(lo + per, n);
    int sum = 0;
    for (int i = lo; i < hi; i++) sum += deg[i];
    s[tid] = sum;
    __syncthreads();
    for (int off = 1; off < 1024; off <<= 1) {
        int t = (tid >= off) ? s[tid - off] : 0;
        __syncthreads();
        s[tid] += t;
        __syncthreads();
    }
    int run = s[tid] - sum;
    for (int i = lo; i < hi; i++) { row_ptr[i] = run; run += deg[i]; }
    if (tid == 1023) row_ptr[n] = s[1023];
}

__global__ void fill_csr_kernel(const int* __restrict__ ei, const int* __restrict__ row_ptr,
                                int* __restrict__ cursor, int* __restrict__ edge_src) {
    int e = blockIdx.x * 256 + threadIdx.x;
    if (e >= ET) return;
    int src, dst;
    if (e < EE) { src = ei[e]; dst = ei[EE + e]; }
    else        { src = e - EE; dst = e - EE; }
    int pos = atomicAdd(&cursor[dst], 1);
    edge_src[row_ptr[dst] + pos] = src;
}

__global__ void dinv_kernel(const int* __restrict__ row_ptr, float* __restrict__ dinv) {
    int n = blockIdx.x * 256 + threadIdx.x;
    if (n >= NN) return;
    int d = row_ptr[n + 1] - row_ptr[n];
    dinv[n] = (d > 0) ? rsqrtf((float)d) : 0.f;
}

// ---- BLOCK-LOCAL degree sort (64-node windows) ----------------------------
// R8 WIN: agg 134->124us, FETCH 155MB (R4-level locality + deg-uniform waves).
__global__ __launch_bounds__(256) void local_sort_kernel(
    const int* __restrict__ row_ptr, int* __restrict__ perm, int n_nodes) {
    int g = blockIdx.x * 4 + (threadIdx.x >> 6);
    int l = threadIdx.x & 63;
    int node = g * 64 + l;
    if (g * 64 >= n_nodes) return;
    int d = (node < n_nodes) ? (row_ptr[node + 1] - row_ptr[node]) : 0x7fffffff;
    int rank = 0;
#pragma unroll 16
    for (int j = 0; j < 64; j++) {
        int dj = __shfl(d, j);
        rank += (dj < d) || (dj == d && j < l);
    }
    if (node < n_nodes) perm[g * 64 + rank] = node;
}

// ---- fold wv into wo: Wvo = wv@wo, bvo = bv@wo + bo (fp32, exact) ----
__global__ void wvwo_kernel(const float* __restrict__ wv, const float* __restrict__ wo,
                            const float* __restrict__ bv, const float* __restrict__ bo,
                            float* __restrict__ Wvo, float* __restrict__ bvo) {
    int l = blockIdx.y;
    const float* Wv = wv + l * 16384;
    const float* Wo = wo + l * 16384;
    int tid = blockIdx.x * 256 + threadIdx.x;
    if (tid < 16384) {
        int r = tid >> 7, c = tid & 127;
        float s = 0.f;
        for (int k = 0; k < 128; k++) s += Wv[r * 128 + k] * Wo[k * 128 + c];
        Wvo[l * 16384 + tid] = s;
    }
    if (blockIdx.x == 0 && threadIdx.x < 128) {
        int c = threadIdx.x;
        float s = bo[l * 128 + c];
        for (int k = 0; k < 128; k++) s += bv[l * 128 + k] * Wo[k * 128 + c];
        bvo[l * 128 + c] = s;
    }
}

// ---- weight prep: fp32 [K,N] (ldb) -> bf16 MFMA B-fragment order ----
__global__ void bprep_kernel(const float* __restrict__ B, short* __restrict__ Bp,
                             int K, int N, int ldb, long srcStride) {
    int layer = blockIdx.y;
    const float* Bsrc = B + srcStride * layer;
    short* Bd = Bp + (size_t)K * N * layer;
    int total = (K >> 5) * (N >> 4) * 64;
    int tid = blockIdx.x * 256 + threadIdx.x;
    if (tid >= total) return;
    int l = tid & 63;
    int rest = tid >> 6;
    int kbc = K >> 5;
    int kb = rest % kbc;
    int c16 = rest / kbc;
    int n = c16 * 16 + (l & 15);
    int kbase = kb * 32 + (l >> 4) * 8;
    short v[8];
#pragma unroll
    for (int j = 0; j < 8; j++) v[j] = f2bf(Bsrc[(size_t)(kbase + j) * ldb + n]);
    *(uint4*)(Bd + (size_t)tid * 8) = *(uint4*)v;
}

__global__ void cast_bf16_kernel(const float* __restrict__ in, short* __restrict__ out, int n4) {
    int i = blockIdx.x * 256 + threadIdx.x;
    if (i >= n4) return;
    float4 v = *(const float4*)(in + (size_t)i * 4);
    short s[4] = { f2bf(v.x), f2bf(v.y), f2bf(v.z), f2bf(v.w) };
    *(uint2*)(out + (size_t)i * 4) = *(uint2*)s;
}

// ---------------- MFMA GEMM, LDS B-staging, XCD-aware column-fast split -----
// TMAJ: store bf16 C tile-major [col/32][row][32]. ATILE32: A tile-major.
// EPI: 0 plain, 2 asad + store
template <int EPI, bool BIAS, bool OUTBF16, int NSPLIT, int KBC,
          bool TMAJ = false, bool ATILE32 = false>
__global__ __launch_bounds__(256) void gemm_bf16_kernel(
    const short* __restrict__ A, const short* __restrict__ Bp,
    const float* __restrict__ bias, void* __restrict__ Cv,
    const float* __restrict__ a_s, const float* __restrict__ a_d,
    float* __restrict__ as_out, float* __restrict__ ad_out, int asH,
    int M, int K, int Nc) {
    __shared__ short Bs[(KBC > 0) ? KBC * 4096 : 8192];
    int t = threadIdx.x;
    int w = t >> 6, l = t & 63;
    int ln = l & 15, lq = l >> 4;
    int MBceil = (M + 63) >> 6;
    int bx = blockIdx.x;
    int xcd = bx & 7, idx = bx >> 3;
    int t2 = idx % NSPLIT;
    int mb = (idx / NSPLIT) * 8 + xcd;
    if (mb >= MBceil) return;
    int bm = mb * 64 + w * 16;
    int arow = bm + ln;
    bool aok = arow < M;
    int rowb = bm + lq * 4;
    const short* Ap = A + (size_t)arow * K + lq * 8;

    auto aload = [&](int kb) -> short8 {
        if (!aok) return (short8){0, 0, 0, 0, 0, 0, 0, 0};
        const short* p;
        if constexpr (ATILE32)
            p = A + ((size_t)kb * M + arow) * 32 + lq * 8;
        else
            p = Ap + kb * 32;
        return *(const short8*)p;
    };

    f32x4 acc[8];
#pragma unroll
    for (int j = 0; j < 8; j++) acc[j] = (f32x4){0.f, 0.f, 0.f, 0.f};

    if constexpr (KBC > 0) {
        {
            const uint4* src = (const uint4*)(Bp + (size_t)t2 * KBC * 4096);
            uint4* dst = (uint4*)Bs;
#pragma unroll
            for (int i = 0; i < KBC * 2; i++)
                dst[i * 256 + t] = src[i * 256 + t];
        }
        short8 af[KBC];
#pragma unroll
        for (int kb = 0; kb < KBC; kb++)
            af[kb] = aload(kb);
        __syncthreads();
#pragma unroll
        for (int kb = 0; kb < KBC; kb++)
#pragma unroll
            for (int ct = 0; ct < 8; ct++) {
                short8 bfr = *(const short8*)(Bs + ((ct * KBC + kb) * 64 + l) * 8);
                acc[ct] = __builtin_amdgcn_mfma_f32_16x16x32_bf16(af[kb], bfr, acc[ct], 0, 0, 0);
            }
    } else {
        int kbc = K >> 5;
        int sct = t >> 5, spart = t & 31;
        auto stage = [&](int buf, int kb) {
            const uint4* src = (const uint4*)(Bp + ((size_t)(t2 * 8 + sct) * kbc + kb) * 512);
            uint4* dst = (uint4*)(Bs + buf * 4096 + sct * 512);
            dst[spart * 2]     = src[spart * 2];
            dst[spart * 2 + 1] = src[spart * 2 + 1];
        };
        stage(0, 0);
        __syncthreads();
        for (int kb = 0; kb < kbc; kb++) {
            if (kb + 1 < kbc) stage((kb + 1) & 1, kb + 1);
            short8 af = aload(kb);
            const short* bsb = Bs + (kb & 1) * 4096;
#pragma unroll
            for (int ct = 0; ct < 8; ct++) {
                short8 bfr = *(const short8*)(bsb + (ct * 64 + l) * 8);
                acc[ct] = __builtin_amdgcn_mfma_f32_16x16x32_bf16(af, bfr, acc[ct], 0, 0, 0);
            }
            __syncthreads();
        }
    }

    if (EPI == 2) {
        const float* asv = a_s + t2 * 128;
        const float* adv = a_d + t2 * 128;
#pragma unroll
        for (int reg = 0; reg < 4; reg++) {
            float vs = 0.f, vd = 0.f;
#pragma unroll
            for (int ct = 0; ct < 8; ct++) {
                int colL = ct * 16 + ln;
                float av = acc[ct][reg];
                vs += av * asv[colL];
                vd += av * adv[colL];
            }
            vs += __shfl_xor(vs, 1); vs += __shfl_xor(vs, 2);
            vs += __shfl_xor(vs, 4); vs += __shfl_xor(vs, 8);
            vd += __shfl_xor(vd, 1); vd += __shfl_xor(vd, 2);
            vd += __shfl_xor(vd, 4); vd += __shfl_xor(vd, 8);
            int row = rowb + reg;
            if (ln == 0 && row < M) {
                as_out[(size_t)row * asH + t2] = vs;
                ad_out[(size_t)row * asH + t2] = vd;
            }
        }
    }
#pragma unroll
    for (int ct = 0; ct < 8; ct++) {
        int col = t2 * 128 + ct * 16 + ln;
        float bv_ = BIAS ? bias[col] : 0.f;
#pragma unroll
        for (int reg = 0; reg < 4; reg++) {
            int row = rowb + reg;
            if (row < M) {
                float v = acc[ct][reg] + bv_;
                if (OUTBF16) {
                    size_t addr;
                    if constexpr (TMAJ)
                        addr = ((size_t)(col >> 5) * M + row) * 32 + (col & 31);
                    else
                        addr = (size_t)row * Nc + col;
                    ((__hip_bfloat16*)Cv)[addr] = __float2bfloat16(v);
                } else {
                    ((float*)Cv)[(size_t)row * Nc + col] = v;
                }
            }
        }
    }
}

// ---- fully fused 6-layer transformer, ASYNC double-buffered staging -------
// R10/R15 = 386us: serial stage (barrier, load 32KB, barrier, compute).
// R11-R14 eliminated occupancy/barrier-count/LDS levers (grid caps 3 blk/CU).
// R16: the untried lever is OVERLAP. Bs -> 2 x 16KB chunks staged via
// __builtin_amdgcn_global_load_lds (async, ZERO data VGPRs -> no R12 cliff);
// each compute chunk issues the NEXT chunk's loads before its MFMAs, and the
// vmcnt(0) the compiler emits at __syncthreads drains them. Same 18
// barriers/layer, same LDS total (50176B), ct-half MFMA order (= R13's,
// bitwise-identical output).
#define TS 136
__global__ __launch_bounds__(256) void transformer_fused_kernel(
    const short* __restrict__ Qb, const short* __restrict__ Wvop,
    const float* __restrict__ bvo, const short* __restrict__ wf1p,
    const short* __restrict__ wf2p, const float* __restrict__ bf1,
    const float* __restrict__ bf2, const float* __restrict__ ln1g,
    const float* __restrict__ ln1b, const float* __restrict__ ln2g,
    const float* __restrict__ ln2b, float* __restrict__ fQ, int M) {
    __shared__ short BsD[16384];         // 2 x 16KB double-buffered weight stage
    __shared__ short Ts[4][16 * TS];     // per-wave T bounce, stride 136
    int t = threadIdx.x;
    int w = t >> 6, l = t & 63;
    int ln = l & 15, lq = l >> 4;
    int MBceil = (M + 63) >> 6;
    int bx = blockIdx.x;
    int xcd = bx & 7, mb = (bx >> 3) * 8 + xcd;
    if (mb >= MBceil) return;
    int bm = mb * 64 + w * 16;
    int rowb = bm + lq * 4;
    short* Tw = &Ts[w][0];

    // load state as C-fragments (col=ct*16+ln, row=rowb+reg)
    ushortT hc[8][4];
#pragma unroll
    for (int ct = 0; ct < 8; ct++) {
        int col = ct * 16 + ln;
#pragma unroll
        for (int reg = 0; reg < 4; reg++) {
            int row = rowb + reg;
            hc[ct][reg] = (row < M) ? ((const ushortT*)Qb)[(size_t)row * 128 + col] : 0;
        }
    }

    // prefetch a linear 16KB chunk into buf (4 calls x 16B/lane; LDS base is
    // wave-uniform, HW scatters lane l to +l*16B)
    auto pfLinear = [&](const short* base, int buf) {
#pragma unroll
        for (int i = 0; i < 4; i++) {
            int off = i * 2048 + w * 512;           // shorts, wave-uniform
            gl16(base + off + l * 8, BsD + buf * 8192 + off);
        }
    };
    // prefetch wf2 ct-half: LDS slot (i*4+w) <- global frag (i+h*4)*16+kc*4+w
    auto pfW2 = [&](const short* w2l, int kc, int h, int buf) {
#pragma unroll
        for (int i = 0; i < 4; i++) {
            int frag = ((i + h * 4) << 4) + kc * 4 + w;
            int slot = i * 4 + w;
            gl16(w2l + frag * 512 + l * 8, BsD + buf * 8192 + slot * 512);
        }
    };
    // 16 MFMAs of one ct-half from buf (slot = ct2*4+kb)
    auto mfmaHalf = [&](f32x4* acc, int half, short8* a, int buf) {
        const short* bsb = BsD + buf * 8192;
#pragma unroll
        for (int kb = 0; kb < 4; kb++)
#pragma unroll
            for (int ct2 = 0; ct2 < 4; ct2++) {
                short8 bfr = *(const short8*)(bsb + ((ct2 * 4 + kb) * 64 + l) * 8);
                acc[half * 4 + ct2] =
                    __builtin_amdgcn_mfma_f32_16x16x32_bf16(a[kb], bfr, acc[half * 4 + ct2], 0, 0, 0);
            }
    };
    // bounce hc (C-frag) -> A-frags via wave-private LDS tile
    auto bounceA = [&](short8* a) {
#pragma unroll
        for (int ct = 0; ct < 8; ct++)
#pragma unroll
            for (int reg = 0; reg < 4; reg++)
                Tw[(lq * 4 + reg) * TS + ct * 16 + ln] = (short)hc[ct][reg];
#pragma unroll
        for (int kb = 0; kb < 4; kb++)
            a[kb] = *(const short8*)(Tw + ln * TS + kb * 32 + lq * 8);
    };
    // residual + bias + LayerNorm over 128 cols; updates hc (bf16-rounded)
    auto lnEpi = [&](f32x4* acc, const float* bias, const float* g,
                     const float* b, bool writeF) {
        float v[8][4];
#pragma unroll
        for (int ct = 0; ct < 8; ct++) {
            float bv_ = bias[ct * 16 + ln];
#pragma unroll
            for (int reg = 0; reg < 4; reg++)
                v[ct][reg] = acc[ct][reg] + bv_ + bf2f(hc[ct][reg]);
        }
#pragma unroll
        for (int reg = 0; reg < 4; reg++) {
            float s = 0.f;
#pragma unroll
            for (int ct = 0; ct < 8; ct++) s += v[ct][reg];
            s += __shfl_xor(s, 1); s += __shfl_xor(s, 2);
            s += __shfl_xor(s, 4); s += __shfl_xor(s, 8);
            float mean = s * (1.f / 128.f);
            float s2 = 0.f;
#pragma unroll
            for (int ct = 0; ct < 8; ct++) { float d = v[ct][reg] - mean; s2 += d * d; }
            s2 += __shfl_xor(s2, 1); s2 += __shfl_xor(s2, 2);
            s2 += __shfl_xor(s2, 4); s2 += __shfl_xor(s2, 8);
            float rstd = rsqrtf(s2 * (1.f / 128.f) + 1e-5f);
            int row = rowb + reg;
#pragma unroll
            for (int ct = 0; ct < 8; ct++) {
                int col = ct * 16 + ln;
                float o = (v[ct][reg] - mean) * rstd * g[col] + b[col];
                hc[ct][reg] = (ushortT)f2bf(o);
                if (writeF && row < M) fQ[(size_t)row * 128 + col] = o;
            }
        }
    };

    int cur = 0;
    pfLinear(Wvop, 0);                   // prologue: layer0 Wvo h0 -> buf0
    __syncthreads();

    for (int lay = 0; lay < LL; lay++) {
        const short* wvl = Wvop + (size_t)lay * 16384;
        const short* w1l = wf1p + (size_t)lay * 65536;
        const short* w2l = wf2p + (size_t)lay * 65536;
        // ---------- g1: acc1 = h @ Wvo (two ct-halves, pipelined) ----------
        short8 a1[4];
        bounceA(a1);
        f32x4 acc1[8];
#pragma unroll
        for (int j = 0; j < 8; j++) acc1[j] = (f32x4){0.f, 0.f, 0.f, 0.f};
        pfLinear(wvl + 8192, cur ^ 1);   // Wvo h1
        mfmaHalf(acc1, 0, a1, cur);
        __syncthreads(); cur ^= 1;
        pfLinear(w1l, cur ^ 1);          // wf1 kc0 h0
        mfmaHalf(acc1, 1, a1, cur);
        lnEpi(acc1, bvo + lay * 128, ln1g + lay * 128, ln1b + lay * 128, false);
        short8 af1[4];
        bounceA(af1);
        __syncthreads(); cur ^= 1;

        // ---------- FF: acc2 = gelu(h@wf1+b1) @ wf2 ----------
        f32x4 acc2[8];
#pragma unroll
        for (int j = 0; j < 8; j++) acc2[j] = (f32x4){0.f, 0.f, 0.f, 0.f};
        for (int kc = 0; kc < 4; kc++) {
            f32x4 acct[8];
#pragma unroll
            for (int j = 0; j < 8; j++) acct[j] = (f32x4){0.f, 0.f, 0.f, 0.f};
            // wf1 kc h0 in buf[cur]; prefetch wf1 kc h1
            pfLinear(w1l + kc * 16384 + 8192, cur ^ 1);
            mfmaHalf(acct, 0, af1, cur);
            __syncthreads(); cur ^= 1;
            // wf1 kc h1; prefetch wf2 kc h0
            pfW2(w2l, kc, 0, cur ^ 1);
            mfmaHalf(acct, 1, af1, cur);
            // gelu + bias -> wave-private T (bf16) -> A2 frags (overlaps pf)
            const float* bfc = bf1 + lay * 512 + kc * 128;
#pragma unroll
            for (int ct = 0; ct < 8; ct++) {
                float bv = bfc[ct * 16 + ln];
#pragma unroll
                for (int reg = 0; reg < 4; reg++)
                    Tw[(lq * 4 + reg) * TS + ct * 16 + ln] = f2bf(gelu_exact(acct[ct][reg] + bv));
            }
            short8 a2[4];
#pragma unroll
            for (int kb2 = 0; kb2 < 4; kb2++)
                a2[kb2] = *(const short8*)(Tw + ln * TS + kb2 * 32 + lq * 8);
            __syncthreads(); cur ^= 1;
            // wf2 kc h0; prefetch wf2 kc h1
            pfW2(w2l, kc, 1, cur ^ 1);
            mfmaHalf(acc2, 0, a2, cur);
            __syncthreads(); cur ^= 1;
            // wf2 kc h1; prefetch next chunk (wf1 kc+1 h0 | next layer Wvo h0)
            if (kc < 3)            pfLinear(w1l + (kc + 1) * 16384, cur ^ 1);
            else if (lay < LL - 1) pfLinear(Wvop + (size_t)(lay + 1) * 16384, cur ^ 1);
            mfmaHalf(acc2, 1, a2, cur);
            __syncthreads(); cur ^= 1;
        }
        lnEpi(acc2, bf2 + lay * 128, ln2g + lay * 128, ln2b + lay * 128, lay == LL - 1);
    }
}

// ---- GAT softmax phase: exact 2-pass per (node, head), 1 wave/node --------
template <int H>
__global__ __launch_bounds__(256) void gat_alpha_kernel(
    const float* __restrict__ as_, const float* __restrict__ ad_,
    const int* __restrict__ row_ptr, const int* __restrict__ edge_src,
    float* __restrict__ exA, float* __restrict__ exS, int n_nodes) {
    const int GS = 64 / H;
    int node = blockIdx.x * 4 + (threadIdx.x >> 6);
    if (node >= n_nodes) return;
    int l = threadIdx.x & 63;
    int h = l / GS;
    int lig = l % GS;
    int start = row_ptr[node];
    int deg = row_ptr[node + 1] - start;
    float adn = ad_[(size_t)node * H + h];
    float m = -1e30f;
    for (int j = lig; j < deg; j += GS) {
        int s = edge_src[start + j];
        float e = as_[(size_t)s * H + h] + adn;
        e = e > 0.f ? e : 0.2f * e;
        m = fmaxf(m, e);
    }
#pragma unroll
    for (int mask = 1; mask < GS; mask <<= 1)
        m = fmaxf(m, __shfl_xor(m, mask));
    float S = 0.f;
    for (int j = lig; j < deg; j += GS) {
        int s = edge_src[start + j];
        float e = as_[(size_t)s * H + h] + adn;
        e = e > 0.f ? e : 0.2f * e;
        float ex = expf(e - m);
        exA[(size_t)h * ET + (start + j)] = ex;
        S += ex;
    }
#pragma unroll
    for (int mask = 1; mask < GS; mask <<= 1)
        S += __shfl_xor(S, mask);
    if (lig == 0) exS[(size_t)h * n_nodes + node] = S;
}

// ---- tiled GAT aggregation: 32-col tiles, XCD-pinned, local-deg-sorted ----
__global__ __launch_bounds__(256) void gat_agg_tiled_kernel(
    const ushortT* __restrict__ hT, const float* __restrict__ exA,
    const float* __restrict__ exS, const float* __restrict__ bias,
    const int* __restrict__ row_ptr, const int* __restrict__ edge_src,
    const int* __restrict__ perm,
    __hip_bfloat16* __restrict__ outT, int n_nodes, int NB) {
    int bx = blockIdx.x;
    int xcd = bx & 7, rest = bx >> 3;
    int tl = rest / NB, nb = rest - tl * NB;
    int tile = tl * 8 + xcd;
    int nl = threadIdx.x >> 2, q = threadIdx.x & 3;
    int idx = nb * 64 + nl;
    if (idx >= n_nodes) return;
    int node = perm[idx];
    int hb = tile >> 2;
    const ushortT* __restrict__ base = hT + (size_t)tile * n_nodes * 32 + q * 8;
    const float* __restrict__ exAh = exA + (size_t)hb * ET;
    int start = row_ptr[node];
    int deg = row_ptr[node + 1] - start;
    float acc[8];
#pragma unroll
    for (int c = 0; c < 8; c++) acc[c] = 0.f;
    for (int j = 0; j < deg; j++) {
        int s = edge_src[start + j];
        float a = exAh[start + j];
        uint4 d = *(const uint4*)(base + (size_t)s * 32);
        accum8(acc, a, d);
    }
    float inv = 1.f / (exS[(size_t)hb * n_nodes + node] + 1e-16f);
    const float* bp = bias + tile * 32 + q * 8;
    short o[8];
#pragma unroll
    for (int c = 0; c < 8; c++)
        o[c] = f2bf(elu1(acc[c] * inv + bp[c]));
    *(uint4*)(outT + ((size_t)tile * n_nodes + node) * 32 + q * 8) = *(uint4*)o;
}

// ---------------- GCN aggregation (bf16 in, row-major) -> bf16 Qb -----------
__global__ __launch_bounds__(256, 2) void gcn_agg_kernel(
    const ushortT* __restrict__ hp, const float* __restrict__ dinv,
    const float* __restrict__ b3, const int* __restrict__ row_ptr,
    const int* __restrict__ edge_src,
    __hip_bfloat16* __restrict__ outb, int n_nodes) {
    int node = blockIdx.x * 2 + (threadIdx.x >> 7);
    int c = threadIdx.x & 127;
    if (node >= n_nodes) return;
    int start = row_ptr[node];
    int deg = row_ptr[node + 1] - start;
    float dn = dinv[node];
    float acc = 0.f;
    auto LS = [&](int j) { return edge_src[start + min(j, deg - 1)]; };
    int s0 = LS(0), s1 = LS(1), s2 = LS(2), s3 = LS(3);
    int s4 = LS(4), s5 = LS(5), s6 = LS(6), s7 = LS(7);
    auto HW = [&](int s, int j, float& h, float& w) {
        h = bf2f(hp[(size_t)s * 128 + c]);
        w = (j < deg) ? dinv[s] * dn : 0.f;
    };
    float h0, h1, h2, h3, h4, h5, h6, h7;
    float w0, w1, w2, w3, w4, w5, w6, w7;
    HW(s0, 0, h0, w0); HW(s1, 1, h1, w1); HW(s2, 2, h2, w2); HW(s3, 3, h3, w3);
    HW(s4, 4, h4, w4); HW(s5, 5, h5, w5); HW(s6, 6, h6, w6); HW(s7, 7, h7, w7);
    int j0 = 0;
    while (true) {
        int jn = j0 + 8;
        bool more = jn < deg;
        float g0, g1, g2, g3, g4, g5, g6, g7;
        float v0 = 0.f, v1 = 0.f, v2 = 0.f, v3 = 0.f;
        float v4 = 0.f, v5 = 0.f, v6 = 0.f, v7 = 0.f;
        if (more) {
            int t0 = LS(jn),     t1 = LS(jn + 1), t2 = LS(jn + 2), t3 = LS(jn + 3);
            int t4 = LS(jn + 4), t5 = LS(jn + 5), t6 = LS(jn + 6), t7 = LS(jn + 7);
            HW(t0, jn,     g0, v0); HW(t1, jn + 1, g1, v1);
            HW(t2, jn + 2, g2, v2); HW(t3, jn + 3, g3, v3);
            HW(t4, jn + 4, g4, v4); HW(t5, jn + 5, g5, v5);
            HW(t6, jn + 6, g6, v6); HW(t7, jn + 7, g7, v7);
        }
        acc += w0 * h0 + w1 * h1 + w2 * h2 + w3 * h3
             + w4 * h4 + w5 * h5 + w6 * h6 + w7 * h7;
        if (!more) break;
        h0 = g0; h1 = g1; h2 = g2; h3 = g3;
        h4 = g4; h5 = g5; h6 = g6; h7 = g7;
        w0 = v0; w1 = v1; w2 = v2; w3 = v3;
        w4 = v4; w5 = v5; w6 = v6; w7 = v7;
        j0 = jn;
    }
    outb[(size_t)node * 128 + c] = __float2bfloat16(elu1(acc + b3[c]));
}

// ---------------- pooling ----------------
__global__ void pool1_kernel(const float* __restrict__ Q, const int* __restrict__ batch,
                             float* __restrict__ psum, float* __restrict__ pmax, int n_nodes) {
    int g = blockIdx.x, seg = blockIdx.y;
    int c = threadIdx.x;
    int lo, hi;
    {
        int l = 0, h = n_nodes;
        while (l < h) { int mid = (l + h) >> 1; if (batch[mid] < g) l = mid + 1; else h = mid; }
        lo = l;
        l = lo; h = n_nodes;
        while (l < h) { int mid = (l + h) >> 1; if (batch[mid] < g + 1) l = mid + 1; else h = mid; }
        hi = l;
    }
    int len = hi - lo;
    int a = lo + (int)((long)len * seg / 8);
    int b = lo + (int)((long)len * (seg + 1) / 8);
    float s = 0.f, mx = -INFINITY;
    for (int n = a; n < b; n++) {
        float v = Q[(size_t)n * 128 + c];
        s += v;
        mx = fmaxf(mx, v);
    }
    psum[(g * 8 + seg) * 128 + c] = s;
    pmax[(g * 8 + seg) * 128 + c] = mx;
}

__global__ void pool2_kernel(const float* __restrict__ psum, const float* __restrict__ pmax,
                             const int* __restrict__ batch,
                             const float* __restrict__ bn1g, const float* __restrict__ bn1b,
                             float* __restrict__ hc, int n_nodes) {
    int g = blockIdx.x;
    int c = threadIdx.x;
    int lo, hi;
    {
        int l = 0, h = n_nodes;
        while (l < h) { int mid = (l + h) >> 1; if (batch[mid] < g) l = mid + 1; else h = mid; }
        lo = l;
        l = lo; h = n_nodes;
        while (l < h) { int mid = (l + h) >> 1; if (batch[mid] < g + 1) l = mid + 1; else h = mid; }
        hi = l;
    }
    int cnt = hi - lo;
    float s = 0.f, mx = -INFINITY;
    for (int seg = 0; seg < 8; seg++) {
        s += psum[(g * 8 + seg) * 128 + c];
        mx = fmaxf(mx, pmax[(g * 8 + seg) * 128 + c]);
    }
    float hm = s / fmaxf((float)cnt, 1.f);
    float hx = (cnt > 0 && isfinite(mx)) ? mx : 0.f;
    const float bn_s = 0.99999500003749968f;
    hc[g * 256 + c]       = hm * bn_s * bn1g[c] + bn1b[c];
    hc[g * 256 + 128 + c] = hx * bn_s * bn1g[128 + c] + bn1b[128 + c];
}

__global__ void head_kernel(const float* __restrict__ hc,
                            const float* __restrict__ fc1w, const float* __restrict__ fc1b,
                            const float* __restrict__ bn2g, const float* __restrict__ bn2b,
                            const float* __restrict__ fc2w, const float* __restrict__ fc2b,
                            float* __restrict__ out) {
    int g = blockIdx.x;
    int j = threadIdx.x;
    const float bn_s = 0.99999500003749968f;
    float acc = fc1b[j];
    for (int i = 0; i < 256; i++) acc += hc[g * 256 + i] * fc1w[i * 64 + j];
    acc = elu1(acc);
    acc = acc * bn_s * bn2g[j] + bn2b[j];
    __shared__ float sv[64];
    sv[j] = acc;
    __syncthreads();
    if (j < 2) {
        float o = fc2b[j];
        for (int i = 0; i < 64; i++) o += sv[i] * fc2w[i * 2 + j];
        out[g * 2 + j] = o;
    }
}

// ---------------- launch ----------------
extern "C" void kernel_launch(void* const* d_in, const int* in_sizes, int n_in,
                              void* d_out, int out_size, void* d_ws, size_t ws_size,
                              hipStream_t stream) {
    const float* x    = (const float*)d_in[0];
    const int*   ei   = (const int*)d_in[1];
    const int*   batch= (const int*)d_in[2];
    const float* W1   = (const float*)d_in[3];
    const float* as1  = (const float*)d_in[4];
    const float* ad1  = (const float*)d_in[5];
    const float* b1   = (const float*)d_in[6];
    const float* W2   = (const float*)d_in[7];
    const float* as2  = (const float*)d_in[8];
    const float* ad2  = (const float*)d_in[9];
    const float* b2   = (const float*)d_in[10];
    const float* W3   = (const float*)d_in[11];
    const float* b3   = (const float*)d_in[12];
    const float* wv   = (const float*)d_in[17];
    const float* bv   = (const float*)d_in[18];
    const float* wo   = (const float*)d_in[19];
    const float* bo   = (const float*)d_in[20];
    const float* ln1g = (const float*)d_in[21];
    const float* ln1b = (const float*)d_in[22];
    const float* ln2g = (const float*)d_in[23];
    const float* ln2b = (const float*)d_in[24];
    const float* wf1  = (const float*)d_in[25];
    const float* bf1  = (const float*)d_in[26];
    const float* wf2  = (const float*)d_in[27];
    const float* bf2  = (const float*)d_in[28];
    const float* bn1g = (const float*)d_in[29];
    const float* bn1b = (const float*)d_in[30];
    const float* fc1w = (const float*)d_in[31];
    const float* fc1b = (const float*)d_in[32];
    const float* bn2g = (const float*)d_in[33];
    const float* bn2b = (const float*)d_in[34];
    const float* fc2w = (const float*)d_in[35];
    const float* fc2b = (const float*)d_in[36];
    float* out = (float*)d_out;

    // ---- workspace layout (bytes), peak ~227 MB ----
    char* wsb = (char*)d_ws;
    short* xb    = (short*)wsb;                        // [N,128] bf16
    float* exAf  = (float*)wsb;                        // [H][ET] (xb dead)
    float* exSf  = (float*)(wsb + 8000000);            // [H][NN]
    short* h1t   = (short*)(wsb + 12800000);           // [32][N][32] tile-major
    short* h2t   = (short*)(wsb + 12800000);           // [16][N][32] (h1t dead)
    short* h3pre = (short*)(wsb + 12800000);           // [N,128] row-major (h2t dead)
    short* bh1   = (short*)(wsb + 115200000);          // [32][N][32] tile-major
    short* bh2   = (short*)(wsb + 115200000);          // [16][N][32] (bh1 dead)
    float* fQ    = (float*)(wsb + 128000000);          // [N,128] fp32 (final state)
    short* Qb    = (short*)(wsb + 153600000);          // [N,128] bf16 transformer in
    char* tail = wsb + 217600000;
    short* W1p  = (short*)tail;  tail += 262144;       // 128x1024
    short* W2p  = (short*)tail;  tail += 1048576;      // 1024x512
    short* W3p  = (short*)tail;  tail += 131072;       // 512x128
    short* Wvop = (short*)tail;  tail += 196608;       // 6 x 128x128
    short* wf1p = (short*)tail;  tail += 786432;       // 6 x 128x512
    short* wf2p = (short*)tail;  tail += 786432;       // 6 x 512x128
    float* Wvo  = (float*)tail;  tail += 393216;       // 6 x 128x128 fp32
    float* bvo  = (float*)tail;  tail += 3072;         // 6 x 128 fp32
    float* fAS  = (float*)tail;  tail += 1600000;      // [N,8]
    float* fAD  = (float*)tail;  tail += 1600000;      // [N,8]
    float* fDv  = (float*)tail;  tail += 200000;
    float* psum = (float*)tail;  tail += 262144;
    float* pmax = (float*)tail;  tail += 262144;
    float* fHC  = (float*)tail;  tail += 65536;
    int* iDeg   = (int*)tail;    tail += 200000;
    int* iRP    = (int*)tail;    tail += 200004;
    int* iCur   = (int*)tail;    tail += 200000;       // also: perm after fill_csr
    int* iES    = (int*)tail;    tail += 1000000;

    hipMemsetAsync(iDeg, 0, NN * sizeof(int), stream);
    hipMemsetAsync(iCur, 0, NN * sizeof(int), stream);

    count_deg_kernel<<<(ET + 255) / 256, 256, 0, stream>>>(ei, iDeg);
    scan_kernel<<<1, 1024, 0, stream>>>(iDeg, iRP, NN);
    fill_csr_kernel<<<(ET + 255) / 256, 256, 0, stream>>>(ei, iRP, iCur, iES);
    dinv_kernel<<<(NN + 255) / 256, 256, 0, stream>>>(iRP, fDv);
    int* perm = iCur;   // dead after fill_csr
    local_sort_kernel<<<(NN / 64 + 4) / 4, 256, 0, stream>>>(iRP, perm, NN);

    wvwo_kernel<<<dim3(64, 6), 256, 0, stream>>>(wv, wo, bv, bo, Wvo, bvo);
    auto bprep = [&](const float* B, short* Bp, int K, int N, int ldb, long sStride, int layers) {
        int total = (K >> 5) * (N >> 4) * 64;
        dim3 grid((total + 255) / 256, layers);
        bprep_kernel<<<grid, 256, 0, stream>>>(B, Bp, K, N, ldb, sStride);
    };
    bprep(W1, W1p, 128, 1024, 1024, 0, 1);
    bprep(W2, W2p, 1024, 512, 512, 0, 1);
    bprep(W3, W3p, 512, 128, 128, 0, 1);
    bprep(Wvo, Wvop, 128, 128, 128, 16384, 6);
    bprep(wf1, wf1p, 128, 512, 512, 65536, 6);
    bprep(wf2, wf2p, 512, 128, 128, 65536, 6);
    cast_bf16_kernel<<<(NN * 128 / 4 + 255) / 256, 256, 0, stream>>>(x, xb, NN * 128 / 4);

    const int MB64 = (NN + 63) / 64;                   // 782
    const int MBp = ((MB64 + 7) / 8) * 8;              // 784
    const int NB = (NN + 63) / 64;                     // 782

    // ---- GAT layer 1 ----
    gemm_bf16_kernel<2, false, true, 8, 4, true, false><<<MBp * 8, 256, 0, stream>>>(
        xb, W1p, nullptr, h1t, as1, ad1, fAS, fAD, 8, NN, 128, 1024);
    gat_alpha_kernel<8><<<(NN + 3) / 4, 256, 0, stream>>>(
        fAS, fAD, iRP, iES, exAf, exSf, NN);
    gat_agg_tiled_kernel<<<4 * NB * 8, 256, 0, stream>>>(
        (const ushortT*)h1t, exAf, exSf, b1, iRP, iES, perm, (__hip_bfloat16*)bh1, NN, NB);
    // ---- GAT layer 2 ----
    gemm_bf16_kernel<2, false, true, 4, 0, true, true><<<MBp * 4, 256, 0, stream>>>(
        bh1, W2p, nullptr, h2t, as2, ad2, fAS, fAD, 4, NN, 1024, 512);
    gat_alpha_kernel<4><<<(NN + 3) / 4, 256, 0, stream>>>(
        fAS, fAD, iRP, iES, exAf, exSf, NN);
    gat_agg_tiled_kernel<<<2 * NB * 8, 256, 0, stream>>>(
        (const ushortT*)h2t, exAf, exSf, b2, iRP, iES, perm, (__hip_bfloat16*)bh2, NN, NB);
    // ---- GCN ----
    gemm_bf16_kernel<0, false, true, 1, 0, false, true><<<MBp, 256, 0, stream>>>(
        bh2, W3p, nullptr, h3pre, nullptr, nullptr, nullptr, nullptr, 0, NN, 512, 128);
    gcn_agg_kernel<<<(NN + 1) / 2, 256, 0, stream>>>(
        (const ushortT*)h3pre, fDv, b3, iRP, iES, (__hip_bfloat16*)Qb, NN);
    // ---- Transformer: all 6 layers, async double-buffered staging ----
    transformer_fused_kernel<<<MBp, 256, 0, stream>>>(
        Qb, Wvop, bvo, wf1p, wf2p, bf1, bf2, ln1g, ln1b, ln2g, ln2b, fQ, NN);
    // ---- pool + head ----
    pool1_kernel<<<dim3(GG, 8), 128, 0, stream>>>(fQ, batch, psum, pmax, NN);
    pool2_kernel<<<GG, 128, 0, stream>>>(psum, pmax, batch, bn1g, bn1b, fHC, NN);
    head_kernel<<<GG, 64, 0, stream>>>(fHC, fc1w, fc1b, bn2g, bn2b, fc2w, fc2b, out);
}